// Round 1
// baseline (18009.995 us; speedup 1.0000x reference)
//
#include <hip/hip_runtime.h>
#include <math.h>

#define NA_TOT 76725
#define NCLS 80
#define CLS_BASE 0
#define LOC_BASE 12276000
#define ANC_BASE 12889800

// ---------------- conv 1x1 (FPN laterals) ----------------
// y[b,o,p] = bias[o] + sum_i x[b,i,p] * w[o,i]
__global__ __launch_bounds__(256) void conv1x1_kernel(
    const float* __restrict__ x, const float* __restrict__ wgt,
    const float* __restrict__ bias, float* __restrict__ y,
    int Cin, int HW) {
  int p = blockIdx.x * blockDim.x + threadIdx.x;
  int o = blockIdx.y;
  int b = blockIdx.z;
  int Cout = gridDim.y;
  if (p >= HW) return;
  const float* xp = x + (size_t)b * Cin * HW + p;
  const float* wp = wgt + (size_t)o * Cin;
  float acc = bias[o];
#pragma unroll 4
  for (int i = 0; i < Cin; ++i) acc = fmaf(xp[(size_t)i * HW], wp[i], acc);
  y[((size_t)b * Cout + o) * HW + p] = acc;
}

// ---------------- nearest 2x upsample + add (in place into dst) ----------------
// dst[b,c,h,w] += src[b,c,h/2,w/2]
__global__ __launch_bounds__(256) void up2add_kernel(
    float* __restrict__ dst, const float* __restrict__ src,
    int C, int H, int W) {
  int idx = blockIdx.x * blockDim.x + threadIdx.x;
  int HW = H * W;
  if (idx >= C * HW) return;
  int b = blockIdx.y;
  int c = idx / HW;
  int p = idx - c * HW;
  int h = p / W;
  int w = p - h * W;
  int Hs = H >> 1, Ws = W >> 1;
  size_t di = ((size_t)b * C + c) * HW + p;
  size_t si = ((size_t)b * C + c) * (Hs * Ws) + (h >> 1) * Ws + (w >> 1);
  dst[di] += src[si];
}

// ---------------- generic conv 3x3, SAME pad ----------------
// MODE 0: plain NCHW output (optional relu)
// MODE 1: classification header: o = a*80+c ; out[((b*NA+off+p*9+a)*80)+c] = sigmoid(acc)
// MODE 2: regression header:     o = a*4+c  ; out[((b*NA+off+p*9+a)*4 )+c] = acc
template <int MODE>
__global__ __launch_bounds__(256) void conv3x3_kernel(
    const float* __restrict__ x, const float* __restrict__ wgt,
    const float* __restrict__ bias, float* __restrict__ y,
    int Cin, int H, int W, int relu, int lvl_off) {
  const int HW = H * W;
  int p = blockIdx.x * blockDim.x + threadIdx.x;
  int o = blockIdx.y;
  int b = blockIdx.z;
  if (p >= HW) return;
  int h = p / W;
  int w = p - h * W;
  const float* xb = x + (size_t)b * Cin * HW;
  const float* wb = wgt + (size_t)o * Cin * 9;
  float acc = bias[o];
  const bool hm = h > 0, hp = h < H - 1, wm = w > 0, wp = w < W - 1;
#pragma unroll 2
  for (int i = 0; i < Cin; ++i) {
    const float* xi = xb + (size_t)i * HW + p;
    const float* wi = wb + i * 9;
    float x00 = (hm && wm) ? xi[-W - 1] : 0.f;
    float x01 = (hm)       ? xi[-W]     : 0.f;
    float x02 = (hm && wp) ? xi[-W + 1] : 0.f;
    float x10 = (wm)       ? xi[-1]     : 0.f;
    float x11 =              xi[0];
    float x12 = (wp)       ? xi[1]      : 0.f;
    float x20 = (hp && wm) ? xi[W - 1]  : 0.f;
    float x21 = (hp)       ? xi[W]      : 0.f;
    float x22 = (hp && wp) ? xi[W + 1]  : 0.f;
    acc = fmaf(x00, wi[0], acc);
    acc = fmaf(x01, wi[1], acc);
    acc = fmaf(x02, wi[2], acc);
    acc = fmaf(x10, wi[3], acc);
    acc = fmaf(x11, wi[4], acc);
    acc = fmaf(x12, wi[5], acc);
    acc = fmaf(x20, wi[6], acc);
    acc = fmaf(x21, wi[7], acc);
    acc = fmaf(x22, wi[8], acc);
  }
  if (MODE == 0) {
    if (relu) acc = fmaxf(acc, 0.f);
    y[((size_t)b * gridDim.y + o) * HW + p] = acc;
  } else if (MODE == 1) {
    int a = o / NCLS;
    int c = o - a * NCLS;
    size_t n = (size_t)b * NA_TOT + lvl_off + (size_t)p * 9 + a;
    y[n * NCLS + c] = 1.f / (1.f + expf(-acc));
  } else {
    int a = o >> 2;
    int c = o & 3;
    size_t n = (size_t)b * NA_TOT + lvl_off + (size_t)p * 9 + a;
    y[n * 4 + c] = acc;
  }
}

// ---------------- anchors (closed form) ----------------
__global__ __launch_bounds__(256) void anchors_kernel(float* __restrict__ out) {
  int n = blockIdx.x * blockDim.x + threadIdx.x;
  if (n >= NA_TOT) return;
  int rem, fw;
  float stride;
  if (n < 57600)      { rem = n;         fw = 80; stride = 8.f; }
  else if (n < 72000) { rem = n - 57600; fw = 40; stride = 16.f; }
  else if (n < 75600) { rem = n - 72000; fw = 20; stride = 32.f; }
  else if (n < 76500) { rem = n - 75600; fw = 10; stride = 64.f; }
  else                { rem = n - 76500; fw = 5;  stride = 128.f; }
  int k = rem % 9;
  int cell = rem / 9;
  int xg = cell % fw;
  int yg = cell / fw;
  const float scales[3] = {1.f, 1.2599210498948732f, 1.5874010519681994f};
  const float isr[3] = {1.4142135623730951f, 1.f, 0.70710678118654755f};
  const float sr[3]  = {0.70710678118654755f, 1.f, 1.4142135623730951f};
  int si = k % 3, ri = k / 3;
  float base = 4.f * stride;
  float wv = base * scales[si] * isr[ri];
  float hv = base * scales[si] * sr[ri];
  float cx = ((float)xg + 0.5f) * stride;
  float cy = ((float)yg + 0.5f) * stride;
  out[(size_t)n * 4 + 0] = cx - 0.5f * wv;
  out[(size_t)n * 4 + 1] = cy - 0.5f * hv;
  out[(size_t)n * 4 + 2] = cx + 0.5f * wv;
  out[(size_t)n * 4 + 3] = cy + 0.5f * hv;
}

extern "C" void kernel_launch(void* const* d_in, const int* in_sizes, int n_in,
                              void* d_out, int out_size, void* d_ws, size_t ws_size,
                              hipStream_t stream) {
  const float* c3 = (const float*)d_in[0];
  const float* c4 = (const float*)d_in[1];
  const float* c5 = (const float*)d_in[2];
  const float* p6 = (const float*)d_in[3];
  const float* p7 = (const float*)d_in[4];
  const float* fl1_w = (const float*)d_in[5];
  const float* fl1_b = (const float*)d_in[6];
  const float* fl2_w = (const float*)d_in[7];
  const float* fl2_b = (const float*)d_in[8];
  const float* fl3_w = (const float*)d_in[9];
  const float* fl3_b = (const float*)d_in[10];
  const float* ftd_w = (const float*)d_in[11];
  const float* ftd_b = (const float*)d_in[12];
  const float* cw[4] = {(const float*)d_in[13], (const float*)d_in[15],
                        (const float*)d_in[17], (const float*)d_in[19]};
  const float* cb[4] = {(const float*)d_in[14], (const float*)d_in[16],
                        (const float*)d_in[18], (const float*)d_in[20]};
  const float* chw = (const float*)d_in[21];
  const float* chb = (const float*)d_in[22];
  const float* rw[4] = {(const float*)d_in[23], (const float*)d_in[25],
                        (const float*)d_in[27], (const float*)d_in[29]};
  const float* rb[4] = {(const float*)d_in[24], (const float*)d_in[26],
                        (const float*)d_in[28], (const float*)d_in[30]};
  const float* rhw = (const float*)d_in[31];
  const float* rhb = (const float*)d_in[32];

  float* ws = (float*)d_ws;
  float* p3l = ws;                 // 2*256*80*80 = 3276800
  float* p4l = ws + 3276800;       // 819200
  float* p5l = ws + 4096000;       // 204800
  float* p3  = ws + 4300800;       // 3276800
  float* p4  = ws + 7577600;       // 819200
  float* p5  = ws + 8396800;       // 204800
  float* t1  = ws + 8601600;       // 3276800
  float* t0  = p3l;                // aliased: p3l dead after FPN

  float* out = (float*)d_out;
  float* out_cls = out + CLS_BASE;
  float* out_loc = out + LOC_BASE;
  float* out_anc = out + ANC_BASE;

  // ---- FPN laterals (1x1) ----
  conv1x1_kernel<<<dim3(2, 256, 2), 256, 0, stream>>>(c5, fl1_w, fl1_b, p5l, 2048, 400);
  conv1x1_kernel<<<dim3(7, 256, 2), 256, 0, stream>>>(c4, fl2_w, fl2_b, p4l, 1024, 1600);
  conv1x1_kernel<<<dim3(25, 256, 2), 256, 0, stream>>>(c3, fl3_w, fl3_b, p3l, 512, 6400);
  // ---- top-down merges ----
  up2add_kernel<<<dim3((256 * 1600 + 255) / 256, 2), 256, 0, stream>>>(p4l, p5l, 256, 40, 40);
  up2add_kernel<<<dim3((256 * 6400 + 255) / 256, 2), 256, 0, stream>>>(p3l, p4l, 256, 80, 80);
  // ---- shared top-down 3x3 conv ----
  conv3x3_kernel<0><<<dim3(2, 256, 2), 256, 0, stream>>>(p5l, ftd_w, ftd_b, p5, 256, 20, 20, 0, 0);
  conv3x3_kernel<0><<<dim3(7, 256, 2), 256, 0, stream>>>(p4l, ftd_w, ftd_b, p4, 256, 40, 40, 0, 0);
  conv3x3_kernel<0><<<dim3(25, 256, 2), 256, 0, stream>>>(p3l, ftd_w, ftd_b, p3, 256, 80, 80, 0, 0);

  // ---- heads over 5 levels ----
  const float* feats[5] = {p3, p4, p5, p6, p7};
  const int Hs[5] = {80, 40, 20, 10, 5};
  const int offs[5] = {0, 57600, 72000, 75600, 76500};
  for (int L = 0; L < 5; ++L) {
    int H = Hs[L], W = Hs[L], HW = H * W;
    dim3 g((HW + 255) / 256, 256, 2);
    dim3 gc((HW + 255) / 256, 720, 2);
    dim3 gr((HW + 255) / 256, 36, 2);
    // classification tower
    conv3x3_kernel<0><<<g, 256, 0, stream>>>(feats[L], cw[0], cb[0], t0, 256, H, W, 1, 0);
    conv3x3_kernel<0><<<g, 256, 0, stream>>>(t0, cw[1], cb[1], t1, 256, H, W, 1, 0);
    conv3x3_kernel<0><<<g, 256, 0, stream>>>(t1, cw[2], cb[2], t0, 256, H, W, 1, 0);
    conv3x3_kernel<0><<<g, 256, 0, stream>>>(t0, cw[3], cb[3], t1, 256, H, W, 1, 0);
    conv3x3_kernel<1><<<gc, 256, 0, stream>>>(t1, chw, chb, out_cls, 256, H, W, 0, offs[L]);
    // regression tower
    conv3x3_kernel<0><<<g, 256, 0, stream>>>(feats[L], rw[0], rb[0], t0, 256, H, W, 1, 0);
    conv3x3_kernel<0><<<g, 256, 0, stream>>>(t0, rw[1], rb[1], t1, 256, H, W, 1, 0);
    conv3x3_kernel<0><<<g, 256, 0, stream>>>(t1, rw[2], rb[2], t0, 256, H, W, 1, 0);
    conv3x3_kernel<0><<<g, 256, 0, stream>>>(t0, rw[3], rb[3], t1, 256, H, W, 1, 0);
    conv3x3_kernel<2><<<gr, 256, 0, stream>>>(t1, rhw, rhb, out_loc, 256, H, W, 0, offs[L]);
  }

  // ---- anchors ----
  anchors_kernel<<<dim3((NA_TOT + 255) / 256), 256, 0, stream>>>(out_anc);
}

// Round 2
// 1538.579 us; speedup vs baseline: 11.7056x; 11.7056x over previous
//
#include <hip/hip_runtime.h>
#include <math.h>

#define NA_TOT 76725
#define NCLS 80
#define LOC_BASE 12276000
#define ANC_BASE 12889800

typedef short s16x8 __attribute__((ext_vector_type(8)));
typedef short s16x4 __attribute__((ext_vector_type(4)));
typedef float fx4 __attribute__((ext_vector_type(4)));

__device__ __forceinline__ unsigned short f2bf(float f) {
  unsigned u = __float_as_uint(f);
  unsigned r = (u + 0x7FFFu + ((u >> 16) & 1u)) >> 16;
  return (unsigned short)r;
}
__device__ __forceinline__ float bf2f(unsigned short h) {
  return __uint_as_float(((unsigned)h) << 16);
}

// ---------------- tiny init: zero buffer for OOB staging source ----------------
__global__ void zk(unsigned short* z) { z[threadIdx.x] = 0; }

// ---------------- weight convert fp32 [O][Cin][kh][kw] -> bf16 [tap][Opad][Cin], zero-padded ----------------
__global__ __launch_bounds__(256) void wconv(const float* __restrict__ src, unsigned short* __restrict__ dst,
                                             int O, int Opad, int Cin, int taps) {
  int idx = blockIdx.x * 256 + threadIdx.x;
  int tot = taps * Opad * Cin;
  if (idx >= tot) return;
  int c = idx % Cin;
  int r = idx / Cin;
  int o = r % Opad;
  int tp = r / Opad;
  float v = (o < O) ? src[((size_t)o * Cin + c) * taps + tp] : 0.f;
  dst[idx] = f2bf(v);
}

// ---------------- activation convert NCHW fp32 -> NHWC bf16 ----------------
__global__ __launch_bounds__(256) void nchw2nhwc(const float* __restrict__ x, unsigned short* __restrict__ y,
                                                 int C, int HW) {
  __shared__ float tile[32][65];
  int pb = blockIdx.x * 64, cb = blockIdx.y * 32, b = blockIdx.z;
  int t = threadIdx.x;
#pragma unroll
  for (int k = 0; k < 8; ++k) {
    int idx = k * 256 + t;
    int c = idx >> 6, p = idx & 63;
    if (pb + p < HW) tile[c][p] = x[((size_t)b * C + cb + c) * HW + pb + p];
  }
  __syncthreads();
  int pix = t >> 2, co = (t & 3) * 8;
  if (pb + pix < HW) {
    s16x8 v;
#pragma unroll
    for (int j = 0; j < 8; ++j) v[j] = (short)f2bf(tile[co + j][pix]);
    *(s16x8*)(y + ((size_t)b * HW + pb + pix) * C + cb + co) = v;
  }
}

// ---------------- nearest 2x upsample + add, NHWC bf16 ----------------
__global__ __launch_bounds__(256) void up2add(unsigned short* __restrict__ dst, const unsigned short* __restrict__ src,
                                              int H, int W, int C8) {
  int idx = blockIdx.x * 256 + threadIdx.x;
  int tot = 2 * H * W * C8;
  if (idx >= tot) return;
  int cv = idx % C8;
  int t = idx / C8;
  int w = t % W; t /= W;
  int h = t % H;
  int b = t / H;
  int Hs = H >> 1, Ws = W >> 1;
  size_t di = ((((size_t)b * H + h) * W + w) * C8 + cv) * 8;
  size_t si = ((((size_t)b * Hs + (h >> 1)) * Ws + (w >> 1)) * C8 + cv) * 8;
  s16x8 d = *(s16x8*)(dst + di);
  s16x8 s = *(const s16x8*)(src + si);
  s16x8 r;
#pragma unroll
  for (int j = 0; j < 8; ++j)
    r[j] = (short)f2bf(bf2f((unsigned short)d[j]) + bf2f((unsigned short)s[j]));
  *(s16x8*)(dst + di) = r;
}

// ---------------- fused multi-level MFMA conv ----------------
// Block: 256 thr = 4 waves; block tile Cout 128 x pixels (16 rows x 16 cols).
// Wave tile 64 (M) x 128 (N=8 rows x 16 cols). K-loop: Cin/32 c-blocks x TAPS taps.
// B staged in LDS ([18x18 halo + pad][32ch] bf16) dbuf via global_load_lds(16B), A from global (L2).
struct LvlParams {
  int nlev;
  int nbcum[6];
  int H[5], W[5], CT[5], RT[5];
  const unsigned short* x[5];
  unsigned short* y0[5];
  unsigned short* y1[5];
  int loff[5];
};

template <int TAPS, int MODE>
__global__ __launch_bounds__(256, 2) void conv_mfma(
    LvlParams P,
    const unsigned short* __restrict__ w0, const unsigned short* __restrict__ w1,
    const float* __restrict__ b0, const float* __restrict__ b1,
    int Cin, int ncb, int Opad, int O, int relu,
    float* __restrict__ fout, const unsigned short* __restrict__ zbuf, int OC) {
  int bx = blockIdx.x;
  int L = 0;
  while (L + 1 < P.nlev && bx >= P.nbcum[L + 1]) ++L;
  int nb = bx - P.nbcum[L];
  int H = P.H[L], W = P.W[L], CT = P.CT[L], RT = P.RT[L];
  int ct = nb % CT;
  int tmp = nb / CT;
  int rt = tmp % RT;
  int b = tmp / RT;
  const unsigned short* x = P.x[L];
  int set = blockIdx.z;
  const unsigned short* wgt = set ? w1 : w0;
  const float* bias = set ? b1 : b0;
  unsigned short* y = set ? P.y1[L] : P.y0[L];

  int tid = threadIdx.x;
  int lane = tid & 63, wv = tid >> 6;
  int wm = wv & 1, wn = wv >> 1;
  int l15 = lane & 15, l4 = lane >> 4;

  __shared__ unsigned short halo[2][384 * 32];

  int r0 = rt * 16 - 1, c0 = ct * 16 - 1;  // halo origin in image coords
  int obase = blockIdx.y * 128 + wm * 64;

  fx4 acc[4][8];
#pragma unroll
  for (int i = 0; i < 4; ++i)
#pragma unroll
    for (int f = 0; f < 8; ++f) acc[i][f] = fx4{0.f, 0.f, 0.f, 0.f};

  auto stage = [&](int buf, int cb) {
#pragma unroll
    for (int s = 0; s < 6; ++s) {
      int ib = wv * 96 + s * 16;  // 4 waves x 96 pixels = 384 slots
      int hp = ib + (lane >> 2);
      int hr = hp / 18, hc = hp - hr * 18;
      int h = r0 + hr, wq = c0 + hc;
      bool ok = (hp < 324) && (h >= 0) && (h < H) && (wq >= 0) && (wq < W);
      const unsigned short* src =
          ok ? (x + (((size_t)b * H + h) * W + wq) * (size_t)Cin + cb * 32 + (lane & 3) * 8) : zbuf;
      unsigned short* dst = &halo[buf][ib * 32];  // wave-uniform base; HW adds lane*16B
      __builtin_amdgcn_global_load_lds((const __attribute__((address_space(1))) unsigned int*)src,
                                       (__attribute__((address_space(3))) unsigned int*)dst, 16, 0, 0);
    }
  };

  stage(0, 0);
  for (int cb = 0; cb < ncb; ++cb) {
    int cur = cb & 1;
    if (cb + 1 < ncb) {
      stage(cur ^ 1, cb + 1);
      asm volatile("s_waitcnt vmcnt(6)" ::: "memory");
    } else {
      asm volatile("s_waitcnt vmcnt(0)" ::: "memory");
    }
    __syncthreads();
#pragma unroll
    for (int t = 0; t < TAPS; ++t) {
      const int dy = (TAPS == 9) ? t / 3 : 1;
      const int dx = (TAPS == 9) ? t % 3 : 1;
      s16x8 a[4];
#pragma unroll
      for (int i = 0; i < 4; ++i) {
        int orow = obase + i * 16 + l15;
        a[i] = *(const s16x8*)(wgt + ((size_t)t * Opad + orow) * Cin + cb * 32 + l4 * 8);
      }
#pragma unroll
      for (int f = 0; f < 8; ++f) {
        int hpix = (wn * 8 + f + dy) * 18 + (l15 + dx);
        s16x8 bf = *(const s16x8*)&halo[cur][hpix * 32 + l4 * 8];
#pragma unroll
        for (int i = 0; i < 4; ++i)
          acc[i][f] = __builtin_amdgcn_mfma_f32_16x16x32_bf16(a[i], bf, acc[i][f], 0, 0, 0);
      }
    }
    __syncthreads();
  }

  // epilogue
  int r_base = rt * 16 + wn * 8;
  int c_img = ct * 16 + l15;
  if (MODE == 0) {
#pragma unroll
    for (int i = 0; i < 4; ++i) {
      fx4 b4 = *(const fx4*)(bias + obase + i * 16 + l4 * 4);
#pragma unroll
      for (int f = 0; f < 8; ++f) {
        int r_img = r_base + f;
        if (r_img < H && c_img < W) {
          size_t base = (((size_t)b * H + r_img) * W + c_img) * OC + obase + i * 16 + l4 * 4;
          s16x4 pk;
#pragma unroll
          for (int j = 0; j < 4; ++j) {
            float v = acc[i][f][j] + b4[j];
            if (relu) v = fmaxf(v, 0.f);
            pk[j] = (short)f2bf(v);
          }
          *(s16x4*)(y + base) = pk;
        }
      }
    }
  } else if (MODE == 1) {
#pragma unroll
    for (int i = 0; i < 4; ++i) {
      int o0 = obase + i * 16 + l4 * 4;
#pragma unroll
      for (int f = 0; f < 8; ++f) {
        int r_img = r_base + f;
        if (r_img < H && c_img < W && o0 < O) {
          int p = r_img * W + c_img;
#pragma unroll
          for (int j = 0; j < 4; ++j) {
            int o = o0 + j;
            int a_ = o / NCLS, c_ = o - a_ * NCLS;
            size_t n = (size_t)b * NA_TOT + P.loff[L] + (size_t)p * 9 + a_;
            float v = acc[i][f][j] + bias[o];
            fout[n * NCLS + c_] = 1.f / (1.f + __expf(-v));
          }
        }
      }
    }
  } else {
#pragma unroll
    for (int i = 0; i < 4; ++i) {
      int o0 = obase + i * 16 + l4 * 4;
#pragma unroll
      for (int f = 0; f < 8; ++f) {
        int r_img = r_base + f;
        if (r_img < H && c_img < W && o0 < O) {
          int p = r_img * W + c_img;
          int a_ = o0 >> 2;
          size_t n = (size_t)b * NA_TOT + P.loff[L] + (size_t)p * 9 + a_;
          fx4 v;
#pragma unroll
          for (int j = 0; j < 4; ++j) v[j] = acc[i][f][j] + bias[o0 + j];
          *(fx4*)(fout + n * 4) = v;
        }
      }
    }
  }
}

// ---------------- anchors (closed form) ----------------
__global__ __launch_bounds__(256) void anchors_kernel(float* __restrict__ out) {
  int n = blockIdx.x * blockDim.x + threadIdx.x;
  if (n >= NA_TOT) return;
  int rem, fw;
  float stride;
  if (n < 57600)      { rem = n;         fw = 80; stride = 8.f; }
  else if (n < 72000) { rem = n - 57600; fw = 40; stride = 16.f; }
  else if (n < 75600) { rem = n - 72000; fw = 20; stride = 32.f; }
  else if (n < 76500) { rem = n - 75600; fw = 10; stride = 64.f; }
  else                { rem = n - 76500; fw = 5;  stride = 128.f; }
  int k = rem % 9;
  int cell = rem / 9;
  int xg = cell % fw;
  int yg = cell / fw;
  const float scales[3] = {1.f, 1.2599210498948732f, 1.5874010519681994f};
  const float isr[3] = {1.4142135623730951f, 1.f, 0.70710678118654755f};
  const float sr[3]  = {0.70710678118654755f, 1.f, 1.4142135623730951f};
  int si = k % 3, ri = k / 3;
  float base = 4.f * stride;
  float wv = base * scales[si] * isr[ri];
  float hv = base * scales[si] * sr[ri];
  float cx = ((float)xg + 0.5f) * stride;
  float cy = ((float)yg + 0.5f) * stride;
  out[(size_t)n * 4 + 0] = cx - 0.5f * wv;
  out[(size_t)n * 4 + 1] = cy - 0.5f * hv;
  out[(size_t)n * 4 + 2] = cx + 0.5f * wv;
  out[(size_t)n * 4 + 3] = cy + 0.5f * hv;
}

// ---------------- workspace layout (bf16/short elements) ----------------
#define W_FL1 0
#define W_FL2 524288
#define W_FL3 786432
#define W_FTD 917504
#define W_CW0 1507328
#define W_RW0 3866624
#define W_CHW 6225920
#define W_RHW 7995392
#define ZBUF_OFF 8290304
#define XP6_OFF 8290368
#define XP7_OFF 8341568
#define P4L_OFF 8354368
#define P5L_OFF 9173568
#define P3L_OFF 9378368
#define P3_OFF 12655168
#define P4_OFF 15931968
#define P5_OFF 16751168
#define T1L0_OFF 16955968
#define T0R_OFF 20232768
#define T1R_OFF 21320768
// total 22,408,768 shorts = 44.8 MB

extern "C" void kernel_launch(void* const* d_in, const int* in_sizes, int n_in,
                              void* d_out, int out_size, void* d_ws, size_t ws_size,
                              hipStream_t stream) {
  const float* c3 = (const float*)d_in[0];
  const float* c4 = (const float*)d_in[1];
  const float* c5 = (const float*)d_in[2];
  const float* p6 = (const float*)d_in[3];
  const float* p7 = (const float*)d_in[4];
  const float* fw_[3] = {(const float*)d_in[5], (const float*)d_in[7], (const float*)d_in[9]};
  const float* fb_[3] = {(const float*)d_in[6], (const float*)d_in[8], (const float*)d_in[10]};
  const float* ftd_w = (const float*)d_in[11];
  const float* ftd_b = (const float*)d_in[12];
  const float* cwf[4] = {(const float*)d_in[13], (const float*)d_in[15], (const float*)d_in[17], (const float*)d_in[19]};
  const float* cbf[4] = {(const float*)d_in[14], (const float*)d_in[16], (const float*)d_in[18], (const float*)d_in[20]};
  const float* chw = (const float*)d_in[21];
  const float* chb = (const float*)d_in[22];
  const float* rwf[4] = {(const float*)d_in[23], (const float*)d_in[25], (const float*)d_in[27], (const float*)d_in[29]};
  const float* rbf[4] = {(const float*)d_in[24], (const float*)d_in[26], (const float*)d_in[28], (const float*)d_in[30]};
  const float* rhw = (const float*)d_in[31];
  const float* rhb = (const float*)d_in[32];

  unsigned short* ws = (unsigned short*)d_ws;
  unsigned short* zbuf = ws + ZBUF_OFF;
  float* out = (float*)d_out;

  // bf16 scratch for converted backbone activations lives in d_out's cls region (dead before headers write)
  unsigned short* x3 = (unsigned short*)d_out;
  unsigned short* x4 = x3 + 6553600;
  unsigned short* x5 = x3 + 9830400;
  unsigned short* xp6 = ws + XP6_OFF;
  unsigned short* xp7 = ws + XP7_OFF;

  // init zero staging source
  zk<<<1, 64, 0, stream>>>(zbuf);

  // weight conversions
  auto wc = [&](const float* s, unsigned short* d, int O, int Opad, int Cin, int taps) {
    int tot = taps * Opad * Cin;
    wconv<<<(tot + 255) / 256, 256, 0, stream>>>(s, d, O, Opad, Cin, taps);
  };
  wc(fw_[0], ws + W_FL1, 256, 256, 2048, 1);
  wc(fw_[1], ws + W_FL2, 256, 256, 1024, 1);
  wc(fw_[2], ws + W_FL3, 256, 256, 512, 1);
  wc(ftd_w, ws + W_FTD, 256, 256, 256, 9);
  for (int k = 0; k < 4; ++k) wc(cwf[k], ws + W_CW0 + k * 589824, 256, 256, 256, 9);
  for (int k = 0; k < 4; ++k) wc(rwf[k], ws + W_RW0 + k * 589824, 256, 256, 256, 9);
  wc(chw, ws + W_CHW, 720, 768, 256, 9);
  wc(rhw, ws + W_RHW, 36, 128, 256, 9);

  // activation conversions
  nchw2nhwc<<<dim3(100, 16, 2), 256, 0, stream>>>(c3, x3, 512, 6400);
  nchw2nhwc<<<dim3(25, 32, 2), 256, 0, stream>>>(c4, x4, 1024, 1600);
  nchw2nhwc<<<dim3(7, 64, 2), 256, 0, stream>>>(c5, x5, 2048, 400);
  nchw2nhwc<<<dim3(2, 8, 2), 256, 0, stream>>>(p6, xp6, 256, 100);
  nchw2nhwc<<<dim3(1, 8, 2), 256, 0, stream>>>(p7, xp7, 256, 25);

  auto mkP = [](int nlev, const int* Hs, const unsigned short* const* xs, unsigned short* const* y0s,
                const int* loffs) {
    LvlParams P{};
    P.nlev = nlev;
    int cum = 0;
    for (int L = 0; L < nlev; ++L) {
      P.nbcum[L] = cum;
      P.H[L] = Hs[L];
      P.W[L] = Hs[L];
      P.CT[L] = (Hs[L] + 15) / 16;
      P.RT[L] = (Hs[L] + 15) / 16;
      cum += 2 * P.CT[L] * P.RT[L];
      P.x[L] = xs[L];
      if (y0s) P.y0[L] = y0s[L];
      if (loffs) P.loff[L] = loffs[L];
    }
    P.nbcum[nlev] = cum;
    return P;
  };

  // ---- FPN laterals (1x1 MFMA conv) ----
  {
    int H5[1] = {20};
    const unsigned short* xs[1] = {x5};
    unsigned short* ys[1] = {ws + P5L_OFF};
    LvlParams P = mkP(1, H5, xs, ys, nullptr);
    conv_mfma<1, 0><<<dim3(P.nbcum[1], 2, 1), 256, 0, stream>>>(P, ws + W_FL1, nullptr, fb_[0], nullptr,
                                                                2048, 64, 256, 256, 0, nullptr, zbuf, 256);
  }
  {
    int H4[1] = {40};
    const unsigned short* xs[1] = {x4};
    unsigned short* ys[1] = {ws + P4L_OFF};
    LvlParams P = mkP(1, H4, xs, ys, nullptr);
    conv_mfma<1, 0><<<dim3(P.nbcum[1], 2, 1), 256, 0, stream>>>(P, ws + W_FL2, nullptr, fb_[1], nullptr,
                                                                1024, 32, 256, 256, 0, nullptr, zbuf, 256);
  }
  {
    int H3[1] = {80};
    const unsigned short* xs[1] = {x3};
    unsigned short* ys[1] = {ws + P3L_OFF};
    LvlParams P = mkP(1, H3, xs, ys, nullptr);
    conv_mfma<1, 0><<<dim3(P.nbcum[1], 2, 1), 256, 0, stream>>>(P, ws + W_FL3, nullptr, fb_[2], nullptr,
                                                                512, 16, 256, 256, 0, nullptr, zbuf, 256);
  }

  // ---- top-down merges (NHWC bf16) ----
  up2add<<<dim3((2 * 40 * 40 * 32 + 255) / 256), 256, 0, stream>>>(ws + P4L_OFF, ws + P5L_OFF, 40, 40, 32);
  up2add<<<dim3((2 * 80 * 80 * 32 + 255) / 256), 256, 0, stream>>>(ws + P3L_OFF, ws + P4L_OFF, 80, 80, 32);

  // ---- shared top-down 3x3 conv (3 levels fused) ----
  {
    int Hs[3] = {80, 40, 20};
    const unsigned short* xs[3] = {ws + P3L_OFF, ws + P4L_OFF, ws + P5L_OFF};
    unsigned short* ys[3] = {ws + P3_OFF, ws + P4_OFF, ws + P5_OFF};
    LvlParams P = mkP(3, Hs, xs, ys, nullptr);
    conv_mfma<9, 0><<<dim3(P.nbcum[3], 2, 1), 256, 0, stream>>>(P, ws + W_FTD, nullptr, ftd_b, nullptr,
                                                                256, 8, 256, 256, 0, nullptr, zbuf, 256);
  }

  // ---- heads: 5 levels fused per layer ----
  int Hs5[5] = {80, 40, 20, 10, 5};
  int loffs[5] = {0, 57600, 72000, 75600, 76500};
  const unsigned short* feats[5] = {ws + P3_OFF, ws + P4_OFF, ws + P5_OFF, xp6, xp7};
  unsigned short* t0s[5] = {ws + P3L_OFF, ws + T0R_OFF, ws + T0R_OFF + 819200, ws + T0R_OFF + 1024000,
                            ws + T0R_OFF + 1075200};
  unsigned short* t1s[5] = {ws + T1L0_OFF, ws + T1R_OFF, ws + T1R_OFF + 819200, ws + T1R_OFF + 1024000,
                            ws + T1R_OFF + 1075200};

  auto tower = [&](const unsigned short* wq, const float* bq, const unsigned short* const* xs,
                   unsigned short* const* ys) {
    LvlParams P = mkP(5, Hs5, xs, ys, nullptr);
    conv_mfma<9, 0><<<dim3(P.nbcum[5], 2, 1), 256, 0, stream>>>(P, wq, nullptr, bq, nullptr,
                                                                256, 8, 256, 256, 1, nullptr, zbuf, 256);
  };

  // classification tower + header
  tower(ws + W_CW0 + 0 * 589824, cbf[0], feats, (unsigned short* const*)t0s);
  tower(ws + W_CW0 + 1 * 589824, cbf[1], (const unsigned short* const*)t0s, (unsigned short* const*)t1s);
  tower(ws + W_CW0 + 2 * 589824, cbf[2], (const unsigned short* const*)t1s, (unsigned short* const*)t0s);
  tower(ws + W_CW0 + 3 * 589824, cbf[3], (const unsigned short* const*)t0s, (unsigned short* const*)t1s);
  {
    LvlParams P = mkP(5, Hs5, (const unsigned short* const*)t1s, nullptr, loffs);
    conv_mfma<9, 1><<<dim3(P.nbcum[5], 6, 1), 256, 0, stream>>>(P, ws + W_CHW, nullptr, chb, nullptr,
                                                                256, 8, 768, 720, 0, out, zbuf, 256);
  }

  // regression tower + header
  tower(ws + W_RW0 + 0 * 589824, rbf[0], feats, (unsigned short* const*)t0s);
  tower(ws + W_RW0 + 1 * 589824, rbf[1], (const unsigned short* const*)t0s, (unsigned short* const*)t1s);
  tower(ws + W_RW0 + 2 * 589824, rbf[2], (const unsigned short* const*)t1s, (unsigned short* const*)t0s);
  tower(ws + W_RW0 + 3 * 589824, rbf[3], (const unsigned short* const*)t0s, (unsigned short* const*)t1s);
  {
    LvlParams P = mkP(5, Hs5, (const unsigned short* const*)t1s, nullptr, loffs);
    conv_mfma<9, 2><<<dim3(P.nbcum[5], 1, 1), 256, 0, stream>>>(P, ws + W_RHW, nullptr, rhb, nullptr,
                                                                256, 8, 128, 36, 0, out + LOC_BASE, zbuf, 256);
  }

  // ---- anchors ----
  anchors_kernel<<<dim3((NA_TOT + 255) / 256), 256, 0, stream>>>(out + ANC_BASE);
}

// Round 3
// 1051.321 us; speedup vs baseline: 17.1308x; 1.4635x over previous
//
#include <hip/hip_runtime.h>
#include <math.h>

#define NA_TOT 76725
#define NCLS 80
#define LOC_BASE 12276000
#define ANC_BASE 12889800

typedef short s16x8 __attribute__((ext_vector_type(8)));
typedef short s16x4 __attribute__((ext_vector_type(4)));
typedef float fx4 __attribute__((ext_vector_type(4)));

__device__ __forceinline__ unsigned short f2bf(float f) {
  unsigned u = __float_as_uint(f);
  unsigned r = (u + 0x7FFFu + ((u >> 16) & 1u)) >> 16;
  return (unsigned short)r;
}
__device__ __forceinline__ float bf2f(unsigned short h) {
  return __uint_as_float(((unsigned)h) << 16);
}

__global__ void zk(unsigned short* z) { z[threadIdx.x] = 0; }

// weight convert fp32 [O][Cin][taps] -> bf16 [tap][cb][Opad][32], zero-padded rows
__global__ __launch_bounds__(256) void wconv(const float* __restrict__ src, unsigned short* __restrict__ dst,
                                             int O, int Opad, int Cin, int taps, int ncb) {
  int idx = blockIdx.x * 256 + threadIdx.x;
  int tot = taps * ncb * Opad * 32;
  if (idx >= tot) return;
  int c32 = idx & 31;
  int r = idx >> 5;
  int o = r % Opad;
  int q = r / Opad;
  int cb = q % ncb;
  int tp = q / ncb;
  int c = cb * 32 + c32;
  float v = (o < O) ? src[((size_t)o * Cin + c) * taps + tp] : 0.f;
  dst[idx] = f2bf(v);
}

// NCHW fp32 -> blocked [b][C/32][HW][32] bf16
__global__ __launch_bounds__(256) void nchw2blk(const float* __restrict__ x, unsigned short* __restrict__ y,
                                                int C, int HW) {
  __shared__ float tile[32][65];
  int pb = blockIdx.x * 64, cb = blockIdx.y, b = blockIdx.z;
  int C32 = C >> 5;
  int t = threadIdx.x;
#pragma unroll
  for (int k = 0; k < 8; ++k) {
    int idx = k * 256 + t;
    int c = idx >> 6, p = idx & 63;
    if (pb + p < HW) tile[c][p] = x[((size_t)b * C + cb * 32 + c) * HW + pb + p];
  }
  __syncthreads();
  int pix = t >> 2, co = (t & 3) * 8;
  if (pb + pix < HW) {
    s16x8 v;
#pragma unroll
    for (int j = 0; j < 8; ++j) v[j] = (short)f2bf(tile[co + j][pix]);
    *(s16x8*)(y + (((size_t)b * C32 + cb) * HW + pb + pix) * 32 + co) = v;
  }
}

// nearest 2x upsample + add, blocked layout
__global__ __launch_bounds__(256) void up2add(unsigned short* __restrict__ dst, const unsigned short* __restrict__ src,
                                              int C32, int H, int W) {
  int idx = blockIdx.x * 256 + threadIdx.x;
  int HW = H * W;
  int tot = 2 * C32 * HW * 4;
  if (idx >= tot) return;
  int cv = idx & 3;
  int t = idx >> 2;
  int p = t % HW; t /= HW;
  int cb = t % C32;
  int b = t / C32;
  int h = p / W, w = p - h * W;
  int Hs = H >> 1, Ws = W >> 1;
  size_t di = (((size_t)b * C32 + cb) * HW + p) * 32 + cv * 8;
  size_t si = (((size_t)b * C32 + cb) * (Hs * Ws) + (h >> 1) * Ws + (w >> 1)) * 32 + cv * 8;
  s16x8 d = *(s16x8*)(dst + di);
  s16x8 s = *(const s16x8*)(src + si);
  s16x8 r;
#pragma unroll
  for (int j = 0; j < 8; ++j)
    r[j] = (short)f2bf(bf2f((unsigned short)d[j]) + bf2f((unsigned short)s[j]));
  *(s16x8*)(dst + di) = r;
}

// ---------------- fused multi-level MFMA conv ----------------
// Block 256 thr = 4 waves. Tile: 128 Cout (grid.y) x (8 rows x 16 cols) pixels.
// Wave: 64 Cout x (4 rows x 16 cols). blockIdx.z selects weight/in/out set (cls vs reg).
struct LvlParams {
  int nlev;
  int nbcum[6];
  int H[5], W[5], CT[5], RT[5], ncb[5], loff[5];
  const unsigned short* x0[5];
  const unsigned short* x1[5];
  const unsigned short* w0[5];
  const unsigned short* w1[5];
  const float* b0[5];
  const float* b1[5];
  unsigned short* y0[5];
  unsigned short* y1[5];
};

template <int TAPS, int MODE>
__global__ __launch_bounds__(256, 4) void conv_mfma(
    LvlParams P, int Opad, int O, int relu, float* __restrict__ fout,
    const unsigned short* __restrict__ zbuf) {
  constexpr int RH = (TAPS == 9) ? 10 : 8;
  constexpr int CW = (TAPS == 9) ? 18 : 16;
  constexpr int NPIX = RH * CW;
  constexpr int SLOTS = (TAPS == 9) ? 192 : 128;
  constexpr int S = (TAPS == 9) ? 3 : 2;
  constexpr int HO = (TAPS == 9) ? 1 : 0;

  int bx = blockIdx.x;
  int L = 0;
  while (L + 1 < P.nlev && bx >= P.nbcum[L + 1]) ++L;
  int nb = bx - P.nbcum[L];
  int H = P.H[L], W = P.W[L], CT = P.CT[L], RT = P.RT[L];
  int ncbL = P.ncb[L];
  int HW = H * W;
  int ct = nb % CT;
  int tmp = nb / CT;
  int rt = tmp % RT;
  int b = tmp / RT;
  int set = blockIdx.z;
  const unsigned short* x = set ? P.x1[L] : P.x0[L];
  const unsigned short* wgt = set ? P.w1[L] : P.w0[L];
  const float* bias = set ? P.b1[L] : P.b0[L];
  unsigned short* y = set ? P.y1[L] : P.y0[L];

  int tid = threadIdx.x;
  int lane = tid & 63, wv = tid >> 6;
  int wm = wv & 1, wn = wv >> 1;
  int l15 = lane & 15, l4 = lane >> 4;

  __shared__ unsigned short halo[2][SLOTS * 32];

  int r0 = rt * 8 - HO, c0 = ct * 16 - HO;
  int obase = blockIdx.y * 128 + wm * 64;

  fx4 acc[4][4];
#pragma unroll
  for (int i = 0; i < 4; ++i)
#pragma unroll
    for (int f = 0; f < 4; ++f) acc[i][f] = fx4{0.f, 0.f, 0.f, 0.f};

  auto stage = [&](int buf, int cb) {
#pragma unroll
    for (int s = 0; s < S; ++s) {
      int ib = wv * (S * 16) + s * 16;
      int hp = ib + (lane >> 2);
      int hr = hp / CW, hc = hp - hr * CW;
      int h = r0 + hr, wq = c0 + hc;
      bool ok = (hp < NPIX) && (h >= 0) && (h < H) && (wq >= 0) && (wq < W);
      int cs = (lane & 3) ^ ((hp >> 1) & 3);  // pre-swizzled source chunk
      const unsigned short* src =
          ok ? (x + (((size_t)b * ncbL + cb) * HW + (h * W + wq)) * 32 + cs * 8) : zbuf;
      unsigned short* dst = &halo[buf][ib * 32];
      __builtin_amdgcn_global_load_lds((const __attribute__((address_space(1))) unsigned int*)src,
                                       (__attribute__((address_space(3))) unsigned int*)dst, 16, 0, 0);
    }
  };

  stage(0, 0);
  for (int cb = 0; cb < ncbL; ++cb) {
    int cur = cb & 1;
    if (cb + 1 < ncbL) {
      stage(cur ^ 1, cb + 1);
      if constexpr (S == 3) asm volatile("s_waitcnt vmcnt(3)" ::: "memory");
      else asm volatile("s_waitcnt vmcnt(2)" ::: "memory");
    } else {
      asm volatile("s_waitcnt vmcnt(0)" ::: "memory");
    }
    __syncthreads();
#pragma unroll
    for (int t = 0; t < TAPS; ++t) {
      const int dy = (TAPS == 9) ? t / 3 : 0;
      const int dx = (TAPS == 9) ? t % 3 : 0;
      s16x8 a[4];
#pragma unroll
      for (int i = 0; i < 4; ++i) {
        int orow = obase + i * 16 + l15;
        a[i] = *(const s16x8*)(wgt + (((size_t)t * ncbL + cb) * Opad + orow) * 32 + l4 * 8);
      }
#pragma unroll
      for (int f = 0; f < 4; ++f) {
        int hpix = (wn * 4 + f + dy) * CW + (l15 + dx);
        s16x8 bfr = *(const s16x8*)&halo[cur][hpix * 32 + (l4 ^ ((hpix >> 1) & 3)) * 8];
#pragma unroll
        for (int i = 0; i < 4; ++i)
          acc[i][f] = __builtin_amdgcn_mfma_f32_16x16x32_bf16(a[i], bfr, acc[i][f], 0, 0, 0);
      }
    }
    __syncthreads();
  }

  int r_base = rt * 8 + wn * 4;
  int c_img = ct * 16 + l15;
  if (MODE == 0) {
    int OC32 = gridDim.y * 4;
#pragma unroll
    for (int i = 0; i < 4; ++i) {
      int o0 = obase + i * 16 + l4 * 4;
      fx4 b4 = *(const fx4*)(bias + o0);
#pragma unroll
      for (int f = 0; f < 4; ++f) {
        int r_img = r_base + f;
        if (r_img < H && c_img < W) {
          int p = r_img * W + c_img;
          size_t base = (((size_t)b * OC32 + (o0 >> 5)) * HW + p) * 32 + (o0 & 31);
          s16x4 pk;
#pragma unroll
          for (int j = 0; j < 4; ++j) {
            float v = acc[i][f][j] + b4[j];
            if (relu) v = fmaxf(v, 0.f);
            pk[j] = (short)f2bf(v);
          }
          *(s16x4*)(y + base) = pk;
        }
      }
    }
  } else if (MODE == 1) {
#pragma unroll
    for (int i = 0; i < 4; ++i) {
      int o0 = obase + i * 16 + l4 * 4;
#pragma unroll
      for (int f = 0; f < 4; ++f) {
        int r_img = r_base + f;
        if (r_img < H && c_img < W && o0 < O) {
          int p = r_img * W + c_img;
#pragma unroll
          for (int j = 0; j < 4; ++j) {
            int o = o0 + j;
            int a_ = o / NCLS, c_ = o - a_ * NCLS;
            size_t n = (size_t)b * NA_TOT + P.loff[L] + (size_t)p * 9 + a_;
            float v = acc[i][f][j] + bias[o];
            fout[n * NCLS + c_] = 1.f / (1.f + __expf(-v));
          }
        }
      }
    }
  } else {
#pragma unroll
    for (int i = 0; i < 4; ++i) {
      int o0 = obase + i * 16 + l4 * 4;
#pragma unroll
      for (int f = 0; f < 4; ++f) {
        int r_img = r_base + f;
        if (r_img < H && c_img < W && o0 < O) {
          int p = r_img * W + c_img;
          int a_ = o0 >> 2;
          size_t n = (size_t)b * NA_TOT + P.loff[L] + (size_t)p * 9 + a_;
          fx4 v;
#pragma unroll
          for (int j = 0; j < 4; ++j) v[j] = acc[i][f][j] + bias[o0 + j];
          *(fx4*)(fout + n * 4) = v;
        }
      }
    }
  }
}

__global__ __launch_bounds__(256) void anchors_kernel(float* __restrict__ out) {
  int n = blockIdx.x * blockDim.x + threadIdx.x;
  if (n >= NA_TOT) return;
  int rem, fw;
  float stride;
  if (n < 57600)      { rem = n;         fw = 80; stride = 8.f; }
  else if (n < 72000) { rem = n - 57600; fw = 40; stride = 16.f; }
  else if (n < 75600) { rem = n - 72000; fw = 20; stride = 32.f; }
  else if (n < 76500) { rem = n - 75600; fw = 10; stride = 64.f; }
  else                { rem = n - 76500; fw = 5;  stride = 128.f; }
  int k = rem % 9;
  int cell = rem / 9;
  int xg = cell % fw;
  int yg = cell / fw;
  const float scales[3] = {1.f, 1.2599210498948732f, 1.5874010519681994f};
  const float isr[3] = {1.4142135623730951f, 1.f, 0.70710678118654755f};
  const float sr[3]  = {0.70710678118654755f, 1.f, 1.4142135623730951f};
  int si = k % 3, ri = k / 3;
  float base = 4.f * stride;
  float wv = base * scales[si] * isr[ri];
  float hv = base * scales[si] * sr[ri];
  float cx = ((float)xg + 0.5f) * stride;
  float cy = ((float)yg + 0.5f) * stride;
  out[(size_t)n * 4 + 0] = cx - 0.5f * wv;
  out[(size_t)n * 4 + 1] = cy - 0.5f * hv;
  out[(size_t)n * 4 + 2] = cx + 0.5f * wv;
  out[(size_t)n * 4 + 3] = cy + 0.5f * hv;
}

// ---------------- ws layout (shorts) ----------------
#define W_FL1 0
#define W_FL2 524288
#define W_FL3 786432
#define W_FTD 917504
#define W_CW0 1507328
#define W_RW0 3866624
#define W_CHW 6225920
#define W_RHW 7995392
#define ZBUF_OFF 8290304
#define RA_OFF 8290368
#define P3_OFF 12655168
#define P4_OFF 15931968
#define P5_OFF 16751168
#define T0C_OFF 16955968
// end 21320768 shorts = 42.6 MB

static const int TL_OFF[5] = {0, 3276800, 4096000, 4300800, 4352000};  // per-level offsets in a t-set

extern "C" void kernel_launch(void* const* d_in, const int* in_sizes, int n_in,
                              void* d_out, int out_size, void* d_ws, size_t ws_size,
                              hipStream_t stream) {
  const float* c3 = (const float*)d_in[0];
  const float* c4 = (const float*)d_in[1];
  const float* c5 = (const float*)d_in[2];
  const float* p6 = (const float*)d_in[3];
  const float* p7 = (const float*)d_in[4];
  const float* flw[3] = {(const float*)d_in[5], (const float*)d_in[7], (const float*)d_in[9]};
  const float* flb[3] = {(const float*)d_in[6], (const float*)d_in[8], (const float*)d_in[10]};
  const float* ftd_w = (const float*)d_in[11];
  const float* ftd_b = (const float*)d_in[12];
  const float* cwf[4] = {(const float*)d_in[13], (const float*)d_in[15], (const float*)d_in[17], (const float*)d_in[19]};
  const float* cbf[4] = {(const float*)d_in[14], (const float*)d_in[16], (const float*)d_in[18], (const float*)d_in[20]};
  const float* chw = (const float*)d_in[21];
  const float* chb = (const float*)d_in[22];
  const float* rwf[4] = {(const float*)d_in[23], (const float*)d_in[25], (const float*)d_in[27], (const float*)d_in[29]};
  const float* rbf[4] = {(const float*)d_in[24], (const float*)d_in[26], (const float*)d_in[28], (const float*)d_in[30]};
  const float* rhw = (const float*)d_in[31];
  const float* rhb = (const float*)d_in[32];

  unsigned short* ws = (unsigned short*)d_ws;
  unsigned short* zbuf = ws + ZBUF_OFF;
  float* out = (float*)d_out;

  // d_out short-region scratch
  unsigned short* ob = (unsigned short*)d_out;
  unsigned short* x3 = ob;
  unsigned short* x4 = ob + 6553600;
  unsigned short* x5 = ob + 9830400;
  unsigned short* t0r = ob;            // after laterals, x region dead
  unsigned short* t1r = ob + 4364800;
  // ws regions
  unsigned short* xp6 = ws + RA_OFF;
  unsigned short* xp7 = ws + RA_OFF + 51200;
  unsigned short* p4l = ws + RA_OFF + 64000;
  unsigned short* p5l = ws + RA_OFF + 883200;
  unsigned short* p3l = ws + RA_OFF + 1088000;
  unsigned short* t1c = ws + RA_OFF;   // reuses RA after ftd/layer1
  unsigned short* t0c = ws + T0C_OFF;
  unsigned short* p3 = ws + P3_OFF;
  unsigned short* p4 = ws + P4_OFF;
  unsigned short* p5 = ws + P5_OFF;

  zk<<<1, 64, 0, stream>>>(zbuf);

  auto wc = [&](const float* s, unsigned short* d, int O, int Opad, int Cin, int taps) {
    int ncb = Cin / 32;
    int tot = taps * ncb * Opad * 32;
    wconv<<<(tot + 255) / 256, 256, 0, stream>>>(s, d, O, Opad, Cin, taps, ncb);
  };
  wc(flw[0], ws + W_FL1, 256, 256, 2048, 1);
  wc(flw[1], ws + W_FL2, 256, 256, 1024, 1);
  wc(flw[2], ws + W_FL3, 256, 256, 512, 1);
  wc(ftd_w, ws + W_FTD, 256, 256, 256, 9);
  for (int k = 0; k < 4; ++k) wc(cwf[k], ws + W_CW0 + k * 589824, 256, 256, 256, 9);
  for (int k = 0; k < 4; ++k) wc(rwf[k], ws + W_RW0 + k * 589824, 256, 256, 256, 9);
  wc(chw, ws + W_CHW, 720, 768, 256, 9);
  wc(rhw, ws + W_RHW, 36, 128, 256, 9);

  nchw2blk<<<dim3(100, 16, 2), 256, 0, stream>>>(c3, x3, 512, 6400);
  nchw2blk<<<dim3(25, 32, 2), 256, 0, stream>>>(c4, x4, 1024, 1600);
  nchw2blk<<<dim3(7, 64, 2), 256, 0, stream>>>(c5, x5, 2048, 400);
  nchw2blk<<<dim3(2, 8, 2), 256, 0, stream>>>(p6, xp6, 256, 100);
  nchw2blk<<<dim3(1, 8, 2), 256, 0, stream>>>(p7, xp7, 256, 25);

  auto fill = [](LvlParams& P, int nlev, const int* Hs) {
    P.nlev = nlev;
    int cum = 0;
    for (int L = 0; L < nlev; ++L) {
      P.nbcum[L] = cum;
      P.H[L] = Hs[L]; P.W[L] = Hs[L];
      P.CT[L] = (Hs[L] + 15) / 16;
      P.RT[L] = (Hs[L] + 7) / 8;
      cum += 2 * P.CT[L] * P.RT[L];
    }
    P.nbcum[nlev] = cum;
  };

  // ---- FPN laterals: 3 levels fused, 1x1 ----
  {
    int Hs[3] = {20, 40, 80};
    LvlParams P{};
    fill(P, 3, Hs);
    P.ncb[0] = 64; P.ncb[1] = 32; P.ncb[2] = 16;
    P.x0[0] = x5; P.x0[1] = x4; P.x0[2] = x3;
    P.w0[0] = ws + W_FL1; P.w0[1] = ws + W_FL2; P.w0[2] = ws + W_FL3;
    P.b0[0] = flb[0]; P.b0[1] = flb[1]; P.b0[2] = flb[2];
    P.y0[0] = p5l; P.y0[1] = p4l; P.y0[2] = p3l;
    conv_mfma<1, 0><<<dim3(P.nbcum[3], 2, 1), 256, 0, stream>>>(P, 256, 256, 0, nullptr, zbuf);
  }
  up2add<<<dim3((2 * 8 * 1600 * 4 + 255) / 256), 256, 0, stream>>>(p4l, p5l, 8, 40, 40);
  up2add<<<dim3((2 * 8 * 6400 * 4 + 255) / 256), 256, 0, stream>>>(p3l, p4l, 8, 80, 80);

  // ---- shared top-down 3x3 ----
  {
    int Hs[3] = {80, 40, 20};
    LvlParams P{};
    fill(P, 3, Hs);
    for (int L = 0; L < 3; ++L) {
      P.ncb[L] = 8;
      P.w0[L] = ws + W_FTD;
      P.b0[L] = ftd_b;
    }
    P.x0[0] = p3l; P.x0[1] = p4l; P.x0[2] = p5l;
    P.y0[0] = p3; P.y0[1] = p4; P.y0[2] = p5;
    conv_mfma<9, 0><<<dim3(P.nbcum[3], 2, 1), 256, 0, stream>>>(P, 256, 256, 0, nullptr, zbuf);
  }

  // ---- towers: 5 levels, cls(z=0)+reg(z=1) fused ----
  int Hs5[5] = {80, 40, 20, 10, 5};
  int loffs[5] = {0, 57600, 72000, 75600, 76500};
  const unsigned short* feats[5] = {p3, p4, p5, xp6, xp7};

  auto towerP = [&](int layer, const unsigned short* const* xc, const unsigned short* const* xr,
                    unsigned short* yc_base, unsigned short* yr_base) {
    LvlParams P{};
    fill(P, 5, Hs5);
    for (int L = 0; L < 5; ++L) {
      P.ncb[L] = 8;
      P.x0[L] = xc[L];
      P.x1[L] = xr ? xr[L] : nullptr;
      P.w0[L] = ws + W_CW0 + layer * 589824;
      P.w1[L] = ws + W_RW0 + layer * 589824;
      P.b0[L] = cbf[layer];
      P.b1[L] = rbf[layer];
      P.y0[L] = yc_base + TL_OFF[L];
      P.y1[L] = yr_base + TL_OFF[L];
    }
    conv_mfma<9, 0><<<dim3(P.nbcum[5], 2, 2), 256, 0, stream>>>(P, 256, 256, 1, nullptr, zbuf);
  };

  const unsigned short* t0c_l[5], *t1c_l[5], *t0r_l[5], *t1r_l[5];
  for (int L = 0; L < 5; ++L) {
    t0c_l[L] = t0c + TL_OFF[L];
    t1c_l[L] = t1c + TL_OFF[L];
    t0r_l[L] = t0r + TL_OFF[L];
    t1r_l[L] = t1r + TL_OFF[L];
  }
  towerP(0, feats, feats, t0c, t0r);
  towerP(1, t0c_l, t0r_l, t1c, t1r);
  towerP(2, t1c_l, t1r_l, t0c, t0r);
  towerP(3, t0c_l, t0r_l, t1c, t1r);

  // ---- reg header first (reads t1r in d_out, writes LOC) ----
  {
    LvlParams P{};
    fill(P, 5, Hs5);
    for (int L = 0; L < 5; ++L) {
      P.ncb[L] = 8;
      P.x0[L] = t1r_l[L];
      P.w0[L] = ws + W_RHW;
      P.b0[L] = rhb;
      P.loff[L] = loffs[L];
    }
    conv_mfma<9, 2><<<dim3(P.nbcum[5], 1, 1), 256, 0, stream>>>(P, 128, 36, 0, out + LOC_BASE, zbuf);
  }
  // ---- cls header (reads t1c in ws, writes cls region — clobbers dead t1r) ----
  {
    LvlParams P{};
    fill(P, 5, Hs5);
    for (int L = 0; L < 5; ++L) {
      P.ncb[L] = 8;
      P.x0[L] = t1c_l[L];
      P.w0[L] = ws + W_CHW;
      P.b0[L] = chb;
      P.loff[L] = loffs[L];
    }
    conv_mfma<9, 1><<<dim3(P.nbcum[5], 6, 1), 256, 0, stream>>>(P, 768, 720, 0, out, zbuf);
  }

  anchors_kernel<<<dim3((NA_TOT + 255) / 256), 256, 0, stream>>>(out + ANC_BASE);
}

// Round 4
// 909.972 us; speedup vs baseline: 19.7918x; 1.1553x over previous
//
#include <hip/hip_runtime.h>
#include <math.h>

#define NA_TOT 76725
#define NCLS 80
#define LOC_BASE 12276000
#define ANC_BASE 12889800

typedef short s16x8 __attribute__((ext_vector_type(8)));
typedef short s16x4 __attribute__((ext_vector_type(4)));
typedef float fx4 __attribute__((ext_vector_type(4)));

__device__ __forceinline__ unsigned short f2bf(float f) {
  unsigned u = __float_as_uint(f);
  unsigned r = (u + 0x7FFFu + ((u >> 16) & 1u)) >> 16;
  return (unsigned short)r;
}
__device__ __forceinline__ float bf2f(unsigned short h) {
  return __uint_as_float(((unsigned)h) << 16);
}

__global__ void zk(unsigned short* z) { z[threadIdx.x] = 0; }

// weight convert fp32 [O][Cin][taps] -> bf16 [tap][cb][Opad][32], zero-padded rows
__global__ __launch_bounds__(256) void wconv(const float* __restrict__ src, unsigned short* __restrict__ dst,
                                             int O, int Opad, int Cin, int taps, int ncb) {
  int idx = blockIdx.x * 256 + threadIdx.x;
  int tot = taps * ncb * Opad * 32;
  if (idx >= tot) return;
  int c32 = idx & 31;
  int r = idx >> 5;
  int o = r % Opad;
  int q = r / Opad;
  int cb = q % ncb;
  int tp = q / ncb;
  int c = cb * 32 + c32;
  float v = (o < O) ? src[((size_t)o * Cin + c) * taps + tp] : 0.f;
  dst[idx] = f2bf(v);
}

// NCHW fp32 -> blocked [b][C/32][HW][32] bf16
__global__ __launch_bounds__(256) void nchw2blk(const float* __restrict__ x, unsigned short* __restrict__ y,
                                                int C, int HW) {
  __shared__ float tile[32][65];
  int pb = blockIdx.x * 64, cb = blockIdx.y, b = blockIdx.z;
  int C32 = C >> 5;
  int t = threadIdx.x;
#pragma unroll
  for (int k = 0; k < 8; ++k) {
    int idx = k * 256 + t;
    int c = idx >> 6, p = idx & 63;
    if (pb + p < HW) tile[c][p] = x[((size_t)b * C + cb * 32 + c) * HW + pb + p];
  }
  __syncthreads();
  int pix = t >> 2, co = (t & 3) * 8;
  if (pb + pix < HW) {
    s16x8 v;
#pragma unroll
    for (int j = 0; j < 8; ++j) v[j] = (short)f2bf(tile[co + j][pix]);
    *(s16x8*)(y + (((size_t)b * C32 + cb) * HW + pb + pix) * 32 + co) = v;
  }
}

// nearest 2x upsample + add, blocked layout
__global__ __launch_bounds__(256) void up2add(unsigned short* __restrict__ dst, const unsigned short* __restrict__ src,
                                              int C32, int H, int W) {
  int idx = blockIdx.x * 256 + threadIdx.x;
  int HW = H * W;
  int tot = 2 * C32 * HW * 4;
  if (idx >= tot) return;
  int cv = idx & 3;
  int t = idx >> 2;
  int p = t % HW; t /= HW;
  int cb = t % C32;
  int b = t / C32;
  int h = p / W, w = p - h * W;
  int Hs = H >> 1, Ws = W >> 1;
  size_t di = (((size_t)b * C32 + cb) * HW + p) * 32 + cv * 8;
  size_t si = (((size_t)b * C32 + cb) * (Hs * Ws) + (h >> 1) * Ws + (w >> 1)) * 32 + cv * 8;
  s16x8 d = *(s16x8*)(dst + di);
  s16x8 s = *(const s16x8*)(src + si);
  s16x8 r;
#pragma unroll
  for (int j = 0; j < 8; ++j)
    r[j] = (short)f2bf(bf2f((unsigned short)d[j]) + bf2f((unsigned short)s[j]));
  *(s16x8*)(dst + di) = r;
}

// ---------------- fused multi-level MFMA conv ----------------
// Block 256 thr = 4 waves. Tile: 64 Cout (grid.y slice) x 128 px (16 col x 8 row).
// Wave: 64 Cout (i=0..3) x 32 px (2 rows via wv, 16 cols). A double-buffered in regs.
struct LvlParams {
  int nlev;
  int nbcum[6];
  int H[5], W[5], CT[5], RT[5], ncb[5], loff[5];
  const unsigned short* x0[5];
  const unsigned short* x1[5];
  const unsigned short* w0[5];
  const unsigned short* w1[5];
  const float* b0[5];
  const float* b1[5];
  unsigned short* y0[5];
  unsigned short* y1[5];
};

template <int TAPS, int MODE>
__global__ __launch_bounds__(256, 4) void conv_mfma(
    LvlParams P, int Opad, int O, int relu, float* __restrict__ fout,
    const unsigned short* __restrict__ zbuf) {
  constexpr int HO = (TAPS == 9) ? 1 : 0;
  constexpr int RH = 8 + 2 * HO;
  constexpr int CW = 16 + 2 * HO;
  constexpr int NPIX = RH * CW;
  constexpr int SLOTS = (TAPS == 9) ? 192 : 128;
  constexpr int S = (TAPS == 9) ? 3 : 2;

  int bx = blockIdx.x;
  int L = 0;
  while (L + 1 < P.nlev && bx >= P.nbcum[L + 1]) ++L;
  int nb = bx - P.nbcum[L];
  int H = P.H[L], W = P.W[L], CT = P.CT[L], RT = P.RT[L];
  int ncbL = P.ncb[L];
  int HW = H * W;
  int ct = nb % CT;
  int tmp = nb / CT;
  int rt = tmp % RT;
  int b = tmp / RT;
  int set = blockIdx.z;
  const unsigned short* x = set ? P.x1[L] : P.x0[L];
  const unsigned short* wgt = set ? P.w1[L] : P.w0[L];
  const float* bias = set ? P.b1[L] : P.b0[L];
  unsigned short* y = set ? P.y1[L] : P.y0[L];

  int tid = threadIdx.x;
  int lane = tid & 63, wv = tid >> 6;
  int l15 = lane & 15, l4 = lane >> 4;

  __shared__ unsigned short halo[2][SLOTS * 32];

  int r0 = rt * 8 - HO, c0 = ct * 16 - HO;
  int obase = blockIdx.y * 64;

  fx4 acc[4][2];
#pragma unroll
  for (int i = 0; i < 4; ++i)
#pragma unroll
    for (int f = 0; f < 2; ++f) acc[i][f] = fx4{0.f, 0.f, 0.f, 0.f};

  auto stage = [&](int buf, int cb) {
#pragma unroll
    for (int s = 0; s < S; ++s) {
      int ib = wv * (S * 16) + s * 16;
      int hp = ib + (lane >> 2);
      int hr = hp / CW, hc = hp - hr * CW;
      int h = r0 + hr, wq = c0 + hc;
      bool ok = (hp < NPIX) && (h >= 0) && (h < H) && (wq >= 0) && (wq < W);
      int cs = (lane & 3) ^ ((hp >> 1) & 3);  // pre-swizzled source chunk
      const unsigned short* src =
          ok ? (x + (((size_t)b * ncbL + cb) * HW + (h * W + wq)) * 32 + cs * 8) : zbuf;
      unsigned short* dst = &halo[buf][ib * 32];
      __builtin_amdgcn_global_load_lds((const __attribute__((address_space(1))) unsigned int*)src,
                                       (__attribute__((address_space(3))) unsigned int*)dst, 16, 0, 0);
    }
  };

  auto loadA = [&](s16x8* a, int cb, int t) {
#pragma unroll
    for (int i = 0; i < 4; ++i)
      a[i] = *(const s16x8*)(wgt + (((size_t)t * ncbL + cb) * Opad + obase + i * 16 + l15) * 32 + l4 * 8);
  };

  s16x8 aC[4], aN[4];
  loadA(aC, 0, 0);
  stage(0, 0);
  for (int cb = 0; cb < ncbL; ++cb) {
    int cur = cb & 1;
    if (cb + 1 < ncbL) {
      stage(cur ^ 1, cb + 1);
      if constexpr (S == 3) asm volatile("s_waitcnt vmcnt(3)" ::: "memory");
      else asm volatile("s_waitcnt vmcnt(2)" ::: "memory");
    } else {
      asm volatile("s_waitcnt vmcnt(0)" ::: "memory");
    }
    __syncthreads();
#pragma unroll
    for (int t = 0; t < TAPS; ++t) {
      // prefetch next tap's (or next cb's) A fragments
      if (t + 1 < TAPS) loadA(aN, cb, t + 1);
      else if (cb + 1 < ncbL) loadA(aN, cb + 1, 0);
      const int dy = (TAPS == 9) ? t / 3 : 0;
      const int dx = (TAPS == 9) ? t % 3 : 0;
#pragma unroll
      for (int f = 0; f < 2; ++f) {
        int hpix = (wv * 2 + f + dy) * CW + (l15 + dx);
        s16x8 bfr = *(const s16x8*)&halo[cur][hpix * 32 + (l4 ^ ((hpix >> 1) & 3)) * 8];
#pragma unroll
        for (int i = 0; i < 4; ++i)
          acc[i][f] = __builtin_amdgcn_mfma_f32_16x16x32_bf16(aC[i], bfr, acc[i][f], 0, 0, 0);
      }
#pragma unroll
      for (int i = 0; i < 4; ++i) aC[i] = aN[i];
    }
    __syncthreads();
  }

  int r_base = rt * 8 + wv * 2;
  int c_img = ct * 16 + l15;
  if (MODE == 0) {
    int OC32 = gridDim.y * 2;
#pragma unroll
    for (int i = 0; i < 4; ++i) {
      int o0 = obase + i * 16 + l4 * 4;
      fx4 b4 = *(const fx4*)(bias + o0);
#pragma unroll
      for (int f = 0; f < 2; ++f) {
        int r_img = r_base + f;
        if (r_img < H && c_img < W) {
          int p = r_img * W + c_img;
          size_t base = (((size_t)b * OC32 + (o0 >> 5)) * HW + p) * 32 + (o0 & 31);
          s16x4 pk;
#pragma unroll
          for (int j = 0; j < 4; ++j) {
            float v = acc[i][f][j] + b4[j];
            if (relu) v = fmaxf(v, 0.f);
            pk[j] = (short)f2bf(v);
          }
          *(s16x4*)(y + base) = pk;
        }
      }
    }
  } else if (MODE == 1) {
#pragma unroll
    for (int i = 0; i < 4; ++i) {
      int o0 = obase + i * 16 + l4 * 4;
#pragma unroll
      for (int f = 0; f < 2; ++f) {
        int r_img = r_base + f;
        if (r_img < H && c_img < W && o0 < O) {
          int p = r_img * W + c_img;
          int a_ = o0 / NCLS, c0 = o0 - a_ * NCLS;
          size_t n = (size_t)b * NA_TOT + P.loff[L] + (size_t)p * 9 + a_;
          fx4 v;
#pragma unroll
          for (int j = 0; j < 4; ++j)
            v[j] = 1.f / (1.f + __expf(-(acc[i][f][j] + bias[o0 + j])));
          *(fx4*)(fout + n * NCLS + c0) = v;
        }
      }
    }
  } else {
#pragma unroll
    for (int i = 0; i < 4; ++i) {
      int o0 = obase + i * 16 + l4 * 4;
#pragma unroll
      for (int f = 0; f < 2; ++f) {
        int r_img = r_base + f;
        if (r_img < H && c_img < W && o0 < O) {
          int p = r_img * W + c_img;
          int a_ = o0 >> 2;
          size_t n = (size_t)b * NA_TOT + P.loff[L] + (size_t)p * 9 + a_;
          fx4 v;
#pragma unroll
          for (int j = 0; j < 4; ++j) v[j] = acc[i][f][j] + bias[o0 + j];
          *(fx4*)(fout + n * 4) = v;
        }
      }
    }
  }
}

__global__ __launch_bounds__(256) void anchors_kernel(float* __restrict__ out) {
  int n = blockIdx.x * blockDim.x + threadIdx.x;
  if (n >= NA_TOT) return;
  int rem, fw;
  float stride;
  if (n < 57600)      { rem = n;         fw = 80; stride = 8.f; }
  else if (n < 72000) { rem = n - 57600; fw = 40; stride = 16.f; }
  else if (n < 75600) { rem = n - 72000; fw = 20; stride = 32.f; }
  else if (n < 76500) { rem = n - 75600; fw = 10; stride = 64.f; }
  else                { rem = n - 76500; fw = 5;  stride = 128.f; }
  int k = rem % 9;
  int cell = rem / 9;
  int xg = cell % fw;
  int yg = cell / fw;
  const float scales[3] = {1.f, 1.2599210498948732f, 1.5874010519681994f};
  const float isr[3] = {1.4142135623730951f, 1.f, 0.70710678118654755f};
  const float sr[3]  = {0.70710678118654755f, 1.f, 1.4142135623730951f};
  int si = k % 3, ri = k / 3;
  float base = 4.f * stride;
  float wv = base * scales[si] * isr[ri];
  float hv = base * scales[si] * sr[ri];
  float cx = ((float)xg + 0.5f) * stride;
  float cy = ((float)yg + 0.5f) * stride;
  out[(size_t)n * 4 + 0] = cx - 0.5f * wv;
  out[(size_t)n * 4 + 1] = cy - 0.5f * hv;
  out[(size_t)n * 4 + 2] = cx + 0.5f * wv;
  out[(size_t)n * 4 + 3] = cy + 0.5f * hv;
}

// ---------------- ws layout (shorts) ----------------
#define W_FL1 0
#define W_FL2 524288
#define W_FL3 786432
#define W_FTD 917504
#define W_CW0 1507328
#define W_RW0 3866624
#define W_CHW 6225920
#define W_RHW 7995392
#define ZBUF_OFF 8290304
#define RA_OFF 8290368
#define P3_OFF 12655168
#define P4_OFF 15931968
#define P5_OFF 16751168
#define T0C_OFF 16955968
// end 21320768 shorts = 42.6 MB

static const int TL_OFF[5] = {0, 3276800, 4096000, 4300800, 4352000};

extern "C" void kernel_launch(void* const* d_in, const int* in_sizes, int n_in,
                              void* d_out, int out_size, void* d_ws, size_t ws_size,
                              hipStream_t stream) {
  const float* c3 = (const float*)d_in[0];
  const float* c4 = (const float*)d_in[1];
  const float* c5 = (const float*)d_in[2];
  const float* p6 = (const float*)d_in[3];
  const float* p7 = (const float*)d_in[4];
  const float* flw[3] = {(const float*)d_in[5], (const float*)d_in[7], (const float*)d_in[9]};
  const float* flb[3] = {(const float*)d_in[6], (const float*)d_in[8], (const float*)d_in[10]};
  const float* ftd_w = (const float*)d_in[11];
  const float* ftd_b = (const float*)d_in[12];
  const float* cwf[4] = {(const float*)d_in[13], (const float*)d_in[15], (const float*)d_in[17], (const float*)d_in[19]};
  const float* cbf[4] = {(const float*)d_in[14], (const float*)d_in[16], (const float*)d_in[18], (const float*)d_in[20]};
  const float* chw = (const float*)d_in[21];
  const float* chb = (const float*)d_in[22];
  const float* rwf[4] = {(const float*)d_in[23], (const float*)d_in[25], (const float*)d_in[27], (const float*)d_in[29]};
  const float* rbf[4] = {(const float*)d_in[24], (const float*)d_in[26], (const float*)d_in[28], (const float*)d_in[30]};
  const float* rhw = (const float*)d_in[31];
  const float* rhb = (const float*)d_in[32];

  unsigned short* ws = (unsigned short*)d_ws;
  unsigned short* zbuf = ws + ZBUF_OFF;
  float* out = (float*)d_out;

  unsigned short* ob = (unsigned short*)d_out;
  unsigned short* x3 = ob;
  unsigned short* x4 = ob + 6553600;
  unsigned short* x5 = ob + 9830400;
  unsigned short* t0r = ob;
  unsigned short* t1r = ob + 4364800;
  unsigned short* xp6 = ws + RA_OFF;
  unsigned short* xp7 = ws + RA_OFF + 51200;
  unsigned short* p4l = ws + RA_OFF + 64000;
  unsigned short* p5l = ws + RA_OFF + 883200;
  unsigned short* p3l = ws + RA_OFF + 1088000;
  unsigned short* t1c = ws + RA_OFF;
  unsigned short* t0c = ws + T0C_OFF;
  unsigned short* p3 = ws + P3_OFF;
  unsigned short* p4 = ws + P4_OFF;
  unsigned short* p5 = ws + P5_OFF;

  zk<<<1, 64, 0, stream>>>(zbuf);

  auto wc = [&](const float* s, unsigned short* d, int O, int Opad, int Cin, int taps) {
    int ncb = Cin / 32;
    int tot = taps * ncb * Opad * 32;
    wconv<<<(tot + 255) / 256, 256, 0, stream>>>(s, d, O, Opad, Cin, taps, ncb);
  };
  wc(flw[0], ws + W_FL1, 256, 256, 2048, 1);
  wc(flw[1], ws + W_FL2, 256, 256, 1024, 1);
  wc(flw[2], ws + W_FL3, 256, 256, 512, 1);
  wc(ftd_w, ws + W_FTD, 256, 256, 256, 9);
  for (int k = 0; k < 4; ++k) wc(cwf[k], ws + W_CW0 + k * 589824, 256, 256, 256, 9);
  for (int k = 0; k < 4; ++k) wc(rwf[k], ws + W_RW0 + k * 589824, 256, 256, 256, 9);
  wc(chw, ws + W_CHW, 720, 768, 256, 9);
  wc(rhw, ws + W_RHW, 36, 64, 256, 9);

  nchw2blk<<<dim3(100, 16, 2), 256, 0, stream>>>(c3, x3, 512, 6400);
  nchw2blk<<<dim3(25, 32, 2), 256, 0, stream>>>(c4, x4, 1024, 1600);
  nchw2blk<<<dim3(7, 64, 2), 256, 0, stream>>>(c5, x5, 2048, 400);
  nchw2blk<<<dim3(2, 8, 2), 256, 0, stream>>>(p6, xp6, 256, 100);
  nchw2blk<<<dim3(1, 8, 2), 256, 0, stream>>>(p7, xp7, 256, 25);

  auto fill = [](LvlParams& P, int nlev, const int* Hs) {
    P.nlev = nlev;
    int cum = 0;
    for (int L = 0; L < nlev; ++L) {
      P.nbcum[L] = cum;
      P.H[L] = Hs[L]; P.W[L] = Hs[L];
      P.CT[L] = (Hs[L] + 15) / 16;
      P.RT[L] = (Hs[L] + 7) / 8;
      cum += 2 * P.CT[L] * P.RT[L];
    }
    P.nbcum[nlev] = cum;
  };

  // ---- FPN laterals: 3 levels fused, 1x1 ----
  {
    int Hs[3] = {20, 40, 80};
    LvlParams P{};
    fill(P, 3, Hs);
    P.ncb[0] = 64; P.ncb[1] = 32; P.ncb[2] = 16;
    P.x0[0] = x5; P.x0[1] = x4; P.x0[2] = x3;
    P.w0[0] = ws + W_FL1; P.w0[1] = ws + W_FL2; P.w0[2] = ws + W_FL3;
    P.b0[0] = flb[0]; P.b0[1] = flb[1]; P.b0[2] = flb[2];
    P.y0[0] = p5l; P.y0[1] = p4l; P.y0[2] = p3l;
    conv_mfma<1, 0><<<dim3(P.nbcum[3], 4, 1), 256, 0, stream>>>(P, 256, 256, 0, nullptr, zbuf);
  }
  up2add<<<dim3((2 * 8 * 1600 * 4 + 255) / 256), 256, 0, stream>>>(p4l, p5l, 8, 40, 40);
  up2add<<<dim3((2 * 8 * 6400 * 4 + 255) / 256), 256, 0, stream>>>(p3l, p4l, 8, 80, 80);

  // ---- shared top-down 3x3 ----
  {
    int Hs[3] = {80, 40, 20};
    LvlParams P{};
    fill(P, 3, Hs);
    for (int L = 0; L < 3; ++L) {
      P.ncb[L] = 8;
      P.w0[L] = ws + W_FTD;
      P.b0[L] = ftd_b;
    }
    P.x0[0] = p3l; P.x0[1] = p4l; P.x0[2] = p5l;
    P.y0[0] = p3; P.y0[1] = p4; P.y0[2] = p5;
    conv_mfma<9, 0><<<dim3(P.nbcum[3], 4, 1), 256, 0, stream>>>(P, 256, 256, 0, nullptr, zbuf);
  }

  // ---- towers: 5 levels, cls(z=0)+reg(z=1) fused ----
  int Hs5[5] = {80, 40, 20, 10, 5};
  int loffs[5] = {0, 57600, 72000, 75600, 76500};
  const unsigned short* feats[5] = {p3, p4, p5, xp6, xp7};

  auto towerP = [&](int layer, const unsigned short* const* xc, const unsigned short* const* xr,
                    unsigned short* yc_base, unsigned short* yr_base) {
    LvlParams P{};
    fill(P, 5, Hs5);
    for (int L = 0; L < 5; ++L) {
      P.ncb[L] = 8;
      P.x0[L] = xc[L];
      P.x1[L] = xr[L];
      P.w0[L] = ws + W_CW0 + layer * 589824;
      P.w1[L] = ws + W_RW0 + layer * 589824;
      P.b0[L] = cbf[layer];
      P.b1[L] = rbf[layer];
      P.y0[L] = yc_base + TL_OFF[L];
      P.y1[L] = yr_base + TL_OFF[L];
    }
    conv_mfma<9, 0><<<dim3(P.nbcum[5], 4, 2), 256, 0, stream>>>(P, 256, 256, 1, nullptr, zbuf);
  };

  const unsigned short* t0c_l[5], *t1c_l[5], *t0r_l[5], *t1r_l[5];
  for (int L = 0; L < 5; ++L) {
    t0c_l[L] = t0c + TL_OFF[L];
    t1c_l[L] = t1c + TL_OFF[L];
    t0r_l[L] = t0r + TL_OFF[L];
    t1r_l[L] = t1r + TL_OFF[L];
  }
  towerP(0, feats, feats, t0c, t0r);
  towerP(1, t0c_l, t0r_l, t1c, t1r);
  towerP(2, t1c_l, t1r_l, t0c, t0r);
  towerP(3, t0c_l, t0r_l, t1c, t1r);

  // ---- reg header first (reads t1r in d_out, writes LOC) ----
  {
    LvlParams P{};
    fill(P, 5, Hs5);
    for (int L = 0; L < 5; ++L) {
      P.ncb[L] = 8;
      P.x0[L] = t1r_l[L];
      P.w0[L] = ws + W_RHW;
      P.b0[L] = rhb;
      P.loff[L] = loffs[L];
    }
    conv_mfma<9, 2><<<dim3(P.nbcum[5], 1, 1), 256, 0, stream>>>(P, 64, 36, 0, out + LOC_BASE, zbuf);
  }
  // ---- cls header (reads t1c in ws, writes cls region) ----
  {
    LvlParams P{};
    fill(P, 5, Hs5);
    for (int L = 0; L < 5; ++L) {
      P.ncb[L] = 8;
      P.x0[L] = t1c_l[L];
      P.w0[L] = ws + W_CHW;
      P.b0[L] = chb;
      P.loff[L] = loffs[L];
    }
    conv_mfma<9, 1><<<dim3(P.nbcum[5], 12, 1), 256, 0, stream>>>(P, 768, 720, 0, out, zbuf);
  }

  anchors_kernel<<<dim3((NA_TOT + 255) / 256), 256, 0, stream>>>(out + ANC_BASE);
}

// Round 5
// 884.582 us; speedup vs baseline: 20.3599x; 1.0287x over previous
//
#include <hip/hip_runtime.h>
#include <math.h>

#define NA_TOT 76725
#define NCLS 80
#define LOC_BASE 12276000
#define ANC_BASE 12889800

typedef short s16x8 __attribute__((ext_vector_type(8)));
typedef short s16x4 __attribute__((ext_vector_type(4)));
typedef float fx4 __attribute__((ext_vector_type(4)));

__device__ __forceinline__ unsigned short f2bf(float f) {
  unsigned u = __float_as_uint(f);
  unsigned r = (u + 0x7FFFu + ((u >> 16) & 1u)) >> 16;
  return (unsigned short)r;
}
__device__ __forceinline__ float bf2f(unsigned short h) {
  return __uint_as_float(((unsigned)h) << 16);
}

__global__ void zk(unsigned short* z) { z[threadIdx.x] = 0; }

// weight convert fp32 [O][Cin][taps] -> bf16 [tap][cb][Opad][32], zero-padded rows
__global__ __launch_bounds__(256) void wconv(const float* __restrict__ src, unsigned short* __restrict__ dst,
                                             int O, int Opad, int Cin, int taps, int ncb) {
  int idx = blockIdx.x * 256 + threadIdx.x;
  int tot = taps * ncb * Opad * 32;
  if (idx >= tot) return;
  int c32 = idx & 31;
  int r = idx >> 5;
  int o = r % Opad;
  int q = r / Opad;
  int cb = q % ncb;
  int tp = q / ncb;
  int c = cb * 32 + c32;
  float v = (o < O) ? src[((size_t)o * Cin + c) * taps + tp] : 0.f;
  dst[idx] = f2bf(v);
}

// NCHW fp32 -> blocked [b][C/32][HW][32] bf16
__global__ __launch_bounds__(256) void nchw2blk(const float* __restrict__ x, unsigned short* __restrict__ y,
                                                int C, int HW) {
  __shared__ float tile[32][65];
  int pb = blockIdx.x * 64, cb = blockIdx.y, b = blockIdx.z;
  int C32 = C >> 5;
  int t = threadIdx.x;
#pragma unroll
  for (int k = 0; k < 8; ++k) {
    int idx = k * 256 + t;
    int c = idx >> 6, p = idx & 63;
    if (pb + p < HW) tile[c][p] = x[((size_t)b * C + cb * 32 + c) * HW + pb + p];
  }
  __syncthreads();
  int pix = t >> 2, co = (t & 3) * 8;
  if (pb + pix < HW) {
    s16x8 v;
#pragma unroll
    for (int j = 0; j < 8; ++j) v[j] = (short)f2bf(tile[co + j][pix]);
    *(s16x8*)(y + (((size_t)b * C32 + cb) * HW + pb + pix) * 32 + co) = v;
  }
}

// nearest 2x upsample + add, blocked layout
__global__ __launch_bounds__(256) void up2add(unsigned short* __restrict__ dst, const unsigned short* __restrict__ src,
                                              int C32, int H, int W) {
  int idx = blockIdx.x * 256 + threadIdx.x;
  int HW = H * W;
  int tot = 2 * C32 * HW * 4;
  if (idx >= tot) return;
  int cv = idx & 3;
  int t = idx >> 2;
  int p = t % HW; t /= HW;
  int cb = t % C32;
  int b = t / C32;
  int h = p / W, w = p - h * W;
  int Hs = H >> 1, Ws = W >> 1;
  size_t di = (((size_t)b * C32 + cb) * HW + p) * 32 + cv * 8;
  size_t si = (((size_t)b * C32 + cb) * (Hs * Ws) + (h >> 1) * Ws + (w >> 1)) * 32 + cv * 8;
  s16x8 d = *(s16x8*)(dst + di);
  s16x8 s = *(const s16x8*)(src + si);
  s16x8 r;
#pragma unroll
  for (int j = 0; j < 8; ++j)
    r[j] = (short)f2bf(bf2f((unsigned short)d[j]) + bf2f((unsigned short)s[j]));
  *(s16x8*)(dst + di) = r;
}

// ---------------- fused multi-level MFMA conv ----------------
// Block 256 thr = 4 waves. Tile: 64 Cout (grid.y slice) x 128 px (16 col x 8 row).
// Wave: 64 Cout (i=0..3) x 32 px (2 rows via wv, 16 cols).
// Raw s_barrier + counted vmcnt; A weights in a depth-3 register ring (2 taps ahead).
struct LvlParams {
  int nlev;
  int nbcum[6];
  int H[5], W[5], CT[5], RT[5], ncb[5], loff[5];
  const unsigned short* x0[5];
  const unsigned short* x1[5];
  const unsigned short* w0[5];
  const unsigned short* w1[5];
  const float* b0[5];
  const float* b1[5];
  unsigned short* y0[5];
  unsigned short* y1[5];
};

#define TAP9(T, USE, PF, PCB, PT)                                                            \
  {                                                                                          \
    loadA(PF, PCB, PT);                                                                      \
    constexpr int dy_ = (T) / 3, dx_ = (T) % 3;                                              \
    _Pragma("unroll") for (int f = 0; f < 2; ++f) {                                          \
      int hpix = (wv * 2 + f + dy_) * CW + (l15 + dx_);                                      \
      s16x8 bfr = *(const s16x8*)&halo[cur][hpix * 32 + ((l4 ^ ((hpix >> 1) & 3)) * 8)];     \
      acc[0][f] = __builtin_amdgcn_mfma_f32_16x16x32_bf16(USE[0], bfr, acc[0][f], 0, 0, 0);  \
      acc[1][f] = __builtin_amdgcn_mfma_f32_16x16x32_bf16(USE[1], bfr, acc[1][f], 0, 0, 0);  \
      acc[2][f] = __builtin_amdgcn_mfma_f32_16x16x32_bf16(USE[2], bfr, acc[2][f], 0, 0, 0);  \
      acc[3][f] = __builtin_amdgcn_mfma_f32_16x16x32_bf16(USE[3], bfr, acc[3][f], 0, 0, 0);  \
    }                                                                                        \
  }

template <int TAPS, int MODE>
__global__ __launch_bounds__(256, 4) void conv_mfma(
    LvlParams P, int Opad, int O, int relu, float* __restrict__ fout,
    const unsigned short* __restrict__ zbuf) {
  constexpr int HO = (TAPS == 9) ? 1 : 0;
  constexpr int RH = 8 + 2 * HO;
  constexpr int CW = 16 + 2 * HO;
  constexpr int NPIX = RH * CW;
  constexpr int SLOTS = (TAPS == 9) ? 192 : 128;
  constexpr int S = (TAPS == 9) ? 3 : 2;

  int bx = blockIdx.x;
  int L = 0;
  while (L + 1 < P.nlev && bx >= P.nbcum[L + 1]) ++L;
  int nb = bx - P.nbcum[L];
  int H = P.H[L], W = P.W[L], CT = P.CT[L], RT = P.RT[L];
  int ncbL = P.ncb[L];
  int HW = H * W;
  int ct = nb % CT;
  int tmp = nb / CT;
  int rt = tmp % RT;
  int b = tmp / RT;
  int set = blockIdx.z;
  const unsigned short* x = set ? P.x1[L] : P.x0[L];
  const unsigned short* wgt = set ? P.w1[L] : P.w0[L];
  const float* bias = set ? P.b1[L] : P.b0[L];
  unsigned short* y = set ? P.y1[L] : P.y0[L];

  int tid = threadIdx.x;
  int lane = tid & 63, wv = tid >> 6;
  int l15 = lane & 15, l4 = lane >> 4;

  __shared__ unsigned short halo[2][SLOTS * 32];

  int r0 = rt * 8 - HO, c0 = ct * 16 - HO;
  int obase = blockIdx.y * 64;

  fx4 acc[4][2];
#pragma unroll
  for (int i = 0; i < 4; ++i)
#pragma unroll
    for (int f = 0; f < 2; ++f) acc[i][f] = fx4{0.f, 0.f, 0.f, 0.f};

  auto stage = [&](int buf, int cb) {
#pragma unroll
    for (int s = 0; s < S; ++s) {
      int ib = wv * (S * 16) + s * 16;
      int hp = ib + (lane >> 2);
      int hr = hp / CW, hc = hp - hr * CW;
      int h = r0 + hr, wq = c0 + hc;
      bool ok = (hp < NPIX) && (h >= 0) && (h < H) && (wq >= 0) && (wq < W);
      int cs = (lane & 3) ^ ((hp >> 1) & 3);  // pre-swizzled source chunk
      const unsigned short* src =
          ok ? (x + (((size_t)b * ncbL + cb) * HW + (h * W + wq)) * 32 + cs * 8) : zbuf;
      unsigned short* dst = &halo[buf][ib * 32];
      __builtin_amdgcn_global_load_lds((const __attribute__((address_space(1))) unsigned int*)src,
                                       (__attribute__((address_space(3))) unsigned int*)dst, 16, 0, 0);
    }
  };

  auto loadA = [&](s16x8* a, int cb, int t) {
#pragma unroll
    for (int i = 0; i < 4; ++i)
      a[i] = *(const s16x8*)(wgt + (((size_t)t * ncbL + cb) * Opad + obase + i * 16 + l15) * 32 + l4 * 8);
  };

  if constexpr (TAPS == 9) {
    s16x8 aR0[4], aR1[4], aR2[4];
    stage(0, 0);
    asm volatile("" ::: "memory");
    loadA(aR0, 0, 0);
    loadA(aR1, 0, 1);
    for (int cb = 0; cb < ncbL; ++cb) {
      int cur = cb & 1;
      int cbn = (cb + 1 < ncbL) ? cb + 1 : cb;
      if (cb + 1 < ncbL) {
        stage(cur ^ 1, cb + 1);
        if (cb == 0) asm volatile("s_waitcnt vmcnt(3)" ::: "memory");
        else asm volatile("s_waitcnt vmcnt(11)" ::: "memory");
      } else {
        asm volatile("s_waitcnt vmcnt(8)" ::: "memory");
      }
      __builtin_amdgcn_s_barrier();
      TAP9(0, aR0, aR2, cb, 2)
      TAP9(1, aR1, aR0, cb, 3)
      TAP9(2, aR2, aR1, cb, 4)
      TAP9(3, aR0, aR2, cb, 5)
      TAP9(4, aR1, aR0, cb, 6)
      TAP9(5, aR2, aR1, cb, 7)
      TAP9(6, aR0, aR2, cb, 8)
      TAP9(7, aR1, aR0, cbn, 0)
      TAP9(8, aR2, aR1, cbn, 1)
      __builtin_amdgcn_s_barrier();
    }
  } else {
    s16x8 aC[4], aN[4];
    stage(0, 0);
    asm volatile("" ::: "memory");
    loadA(aC, 0, 0);
    for (int cb = 0; cb < ncbL; ++cb) {
      int cur = cb & 1;
      if (cb + 1 < ncbL) {
        stage(cur ^ 1, cb + 1);
        asm volatile("s_waitcnt vmcnt(2)" ::: "memory");
      } else {
        asm volatile("s_waitcnt vmcnt(0)" ::: "memory");
      }
      __builtin_amdgcn_s_barrier();
      loadA(aN, (cb + 1 < ncbL) ? cb + 1 : cb, 0);
#pragma unroll
      for (int f = 0; f < 2; ++f) {
        int hpix = (wv * 2 + f) * CW + l15;
        s16x8 bfr = *(const s16x8*)&halo[cur][hpix * 32 + ((l4 ^ ((hpix >> 1) & 3)) * 8)];
#pragma unroll
        for (int i = 0; i < 4; ++i)
          acc[i][f] = __builtin_amdgcn_mfma_f32_16x16x32_bf16(aC[i], bfr, acc[i][f], 0, 0, 0);
      }
#pragma unroll
      for (int i = 0; i < 4; ++i) aC[i] = aN[i];
      __builtin_amdgcn_s_barrier();
    }
  }

  int r_base = rt * 8 + wv * 2;
  int c_img = ct * 16 + l15;
  if (MODE == 0) {
    int OC32 = gridDim.y * 2;
#pragma unroll
    for (int i = 0; i < 4; ++i) {
      int o0 = obase + i * 16 + l4 * 4;
      fx4 b4 = *(const fx4*)(bias + o0);
#pragma unroll
      for (int f = 0; f < 2; ++f) {
        int r_img = r_base + f;
        if (r_img < H && c_img < W) {
          int p = r_img * W + c_img;
          size_t base = (((size_t)b * OC32 + (o0 >> 5)) * HW + p) * 32 + (o0 & 31);
          s16x4 pk;
#pragma unroll
          for (int j = 0; j < 4; ++j) {
            float v = acc[i][f][j] + b4[j];
            if (relu) v = fmaxf(v, 0.f);
            pk[j] = (short)f2bf(v);
          }
          *(s16x4*)(y + base) = pk;
        }
      }
    }
  } else if (MODE == 1) {
#pragma unroll
    for (int i = 0; i < 4; ++i) {
      int o0 = obase + i * 16 + l4 * 4;
#pragma unroll
      for (int f = 0; f < 2; ++f) {
        int r_img = r_base + f;
        if (r_img < H && c_img < W && o0 < O) {
          int p = r_img * W + c_img;
          int a_ = o0 / NCLS, c0i = o0 - a_ * NCLS;
          size_t n = (size_t)b * NA_TOT + P.loff[L] + (size_t)p * 9 + a_;
          fx4 v;
#pragma unroll
          for (int j = 0; j < 4; ++j)
            v[j] = 1.f / (1.f + __expf(-(acc[i][f][j] + bias[o0 + j])));
          *(fx4*)(fout + n * NCLS + c0i) = v;
        }
      }
    }
  } else {
#pragma unroll
    for (int i = 0; i < 4; ++i) {
      int o0 = obase + i * 16 + l4 * 4;
#pragma unroll
      for (int f = 0; f < 2; ++f) {
        int r_img = r_base + f;
        if (r_img < H && c_img < W && o0 < O) {
          int p = r_img * W + c_img;
          int a_ = o0 >> 2;
          size_t n = (size_t)b * NA_TOT + P.loff[L] + (size_t)p * 9 + a_;
          fx4 v;
#pragma unroll
          for (int j = 0; j < 4; ++j) v[j] = acc[i][f][j] + bias[o0 + j];
          *(fx4*)(fout + n * 4) = v;
        }
      }
    }
  }
}

__global__ __launch_bounds__(256) void anchors_kernel(float* __restrict__ out) {
  int n = blockIdx.x * blockDim.x + threadIdx.x;
  if (n >= NA_TOT) return;
  int rem, fw;
  float stride;
  if (n < 57600)      { rem = n;         fw = 80; stride = 8.f; }
  else if (n < 72000) { rem = n - 57600; fw = 40; stride = 16.f; }
  else if (n < 75600) { rem = n - 72000; fw = 20; stride = 32.f; }
  else if (n < 76500) { rem = n - 75600; fw = 10; stride = 64.f; }
  else                { rem = n - 76500; fw = 5;  stride = 128.f; }
  int k = rem % 9;
  int cell = rem / 9;
  int xg = cell % fw;
  int yg = cell / fw;
  const float scales[3] = {1.f, 1.2599210498948732f, 1.5874010519681994f};
  const float isr[3] = {1.4142135623730951f, 1.f, 0.70710678118654755f};
  const float sr[3]  = {0.70710678118654755f, 1.f, 1.4142135623730951f};
  int si = k % 3, ri = k / 3;
  float base = 4.f * stride;
  float wv = base * scales[si] * isr[ri];
  float hv = base * scales[si] * sr[ri];
  float cx = ((float)xg + 0.5f) * stride;
  float cy = ((float)yg + 0.5f) * stride;
  out[(size_t)n * 4 + 0] = cx - 0.5f * wv;
  out[(size_t)n * 4 + 1] = cy - 0.5f * hv;
  out[(size_t)n * 4 + 2] = cx + 0.5f * wv;
  out[(size_t)n * 4 + 3] = cy + 0.5f * hv;
}

// ---------------- ws layout (shorts) ----------------
#define W_FL1 0
#define W_FL2 524288
#define W_FL3 786432
#define W_FTD 917504
#define W_CW0 1507328
#define W_RW0 3866624
#define W_CHW 6225920
#define W_RHW 7995392
#define ZBUF_OFF 8290304
#define RA_OFF 8290368
#define P3_OFF 12655168
#define P4_OFF 15931968
#define P5_OFF 16751168
#define T0C_OFF 16955968
// end 21320768 shorts = 42.6 MB

static const int TL_OFF[5] = {0, 3276800, 4096000, 4300800, 4352000};

extern "C" void kernel_launch(void* const* d_in, const int* in_sizes, int n_in,
                              void* d_out, int out_size, void* d_ws, size_t ws_size,
                              hipStream_t stream) {
  const float* c3 = (const float*)d_in[0];
  const float* c4 = (const float*)d_in[1];
  const float* c5 = (const float*)d_in[2];
  const float* p6 = (const float*)d_in[3];
  const float* p7 = (const float*)d_in[4];
  const float* flw[3] = {(const float*)d_in[5], (const float*)d_in[7], (const float*)d_in[9]};
  const float* flb[3] = {(const float*)d_in[6], (const float*)d_in[8], (const float*)d_in[10]};
  const float* ftd_w = (const float*)d_in[11];
  const float* ftd_b = (const float*)d_in[12];
  const float* cwf[4] = {(const float*)d_in[13], (const float*)d_in[15], (const float*)d_in[17], (const float*)d_in[19]};
  const float* cbf[4] = {(const float*)d_in[14], (const float*)d_in[16], (const float*)d_in[18], (const float*)d_in[20]};
  const float* chw = (const float*)d_in[21];
  const float* chb = (const float*)d_in[22];
  const float* rwf[4] = {(const float*)d_in[23], (const float*)d_in[25], (const float*)d_in[27], (const float*)d_in[29]};
  const float* rbf[4] = {(const float*)d_in[24], (const float*)d_in[26], (const float*)d_in[28], (const float*)d_in[30]};
  const float* rhw = (const float*)d_in[31];
  const float* rhb = (const float*)d_in[32];

  unsigned short* ws = (unsigned short*)d_ws;
  unsigned short* zbuf = ws + ZBUF_OFF;
  float* out = (float*)d_out;

  unsigned short* ob = (unsigned short*)d_out;
  unsigned short* x3 = ob;
  unsigned short* x4 = ob + 6553600;
  unsigned short* x5 = ob + 9830400;
  unsigned short* t0r = ob;
  unsigned short* t1r = ob + 4364800;
  unsigned short* xp6 = ws + RA_OFF;
  unsigned short* xp7 = ws + RA_OFF + 51200;
  unsigned short* p4l = ws + RA_OFF + 64000;
  unsigned short* p5l = ws + RA_OFF + 883200;
  unsigned short* p3l = ws + RA_OFF + 1088000;
  unsigned short* t1c = ws + RA_OFF;
  unsigned short* t0c = ws + T0C_OFF;
  unsigned short* p3 = ws + P3_OFF;
  unsigned short* p4 = ws + P4_OFF;
  unsigned short* p5 = ws + P5_OFF;

  zk<<<1, 64, 0, stream>>>(zbuf);

  auto wc = [&](const float* s, unsigned short* d, int O, int Opad, int Cin, int taps) {
    int ncb = Cin / 32;
    int tot = taps * ncb * Opad * 32;
    wconv<<<(tot + 255) / 256, 256, 0, stream>>>(s, d, O, Opad, Cin, taps, ncb);
  };
  wc(flw[0], ws + W_FL1, 256, 256, 2048, 1);
  wc(flw[1], ws + W_FL2, 256, 256, 1024, 1);
  wc(flw[2], ws + W_FL3, 256, 256, 512, 1);
  wc(ftd_w, ws + W_FTD, 256, 256, 256, 9);
  for (int k = 0; k < 4; ++k) wc(cwf[k], ws + W_CW0 + k * 589824, 256, 256, 256, 9);
  for (int k = 0; k < 4; ++k) wc(rwf[k], ws + W_RW0 + k * 589824, 256, 256, 256, 9);
  wc(chw, ws + W_CHW, 720, 768, 256, 9);
  wc(rhw, ws + W_RHW, 36, 64, 256, 9);

  nchw2blk<<<dim3(100, 16, 2), 256, 0, stream>>>(c3, x3, 512, 6400);
  nchw2blk<<<dim3(25, 32, 2), 256, 0, stream>>>(c4, x4, 1024, 1600);
  nchw2blk<<<dim3(7, 64, 2), 256, 0, stream>>>(c5, x5, 2048, 400);
  nchw2blk<<<dim3(2, 8, 2), 256, 0, stream>>>(p6, xp6, 256, 100);
  nchw2blk<<<dim3(1, 8, 2), 256, 0, stream>>>(p7, xp7, 256, 25);

  auto fill = [](LvlParams& P, int nlev, const int* Hs) {
    P.nlev = nlev;
    int cum = 0;
    for (int L = 0; L < nlev; ++L) {
      P.nbcum[L] = cum;
      P.H[L] = Hs[L]; P.W[L] = Hs[L];
      P.CT[L] = (Hs[L] + 15) / 16;
      P.RT[L] = (Hs[L] + 7) / 8;
      cum += 2 * P.CT[L] * P.RT[L];
    }
    P.nbcum[nlev] = cum;
  };

  // ---- FPN laterals: 3 levels fused, 1x1 ----
  {
    int Hs[3] = {20, 40, 80};
    LvlParams P{};
    fill(P, 3, Hs);
    P.ncb[0] = 64; P.ncb[1] = 32; P.ncb[2] = 16;
    P.x0[0] = x5; P.x0[1] = x4; P.x0[2] = x3;
    P.w0[0] = ws + W_FL1; P.w0[1] = ws + W_FL2; P.w0[2] = ws + W_FL3;
    P.b0[0] = flb[0]; P.b0[1] = flb[1]; P.b0[2] = flb[2];
    P.y0[0] = p5l; P.y0[1] = p4l; P.y0[2] = p3l;
    conv_mfma<1, 0><<<dim3(P.nbcum[3], 4, 1), 256, 0, stream>>>(P, 256, 256, 0, nullptr, zbuf);
  }
  up2add<<<dim3((2 * 8 * 1600 * 4 + 255) / 256), 256, 0, stream>>>(p4l, p5l, 8, 40, 40);
  up2add<<<dim3((2 * 8 * 6400 * 4 + 255) / 256), 256, 0, stream>>>(p3l, p4l, 8, 80, 80);

  // ---- shared top-down 3x3 ----
  {
    int Hs[3] = {80, 40, 20};
    LvlParams P{};
    fill(P, 3, Hs);
    for (int L = 0; L < 3; ++L) {
      P.ncb[L] = 8;
      P.w0[L] = ws + W_FTD;
      P.b0[L] = ftd_b;
    }
    P.x0[0] = p3l; P.x0[1] = p4l; P.x0[2] = p5l;
    P.y0[0] = p3; P.y0[1] = p4; P.y0[2] = p5;
    conv_mfma<9, 0><<<dim3(P.nbcum[3], 4, 1), 256, 0, stream>>>(P, 256, 256, 0, nullptr, zbuf);
  }

  // ---- towers: 5 levels, cls(z=0)+reg(z=1) fused ----
  int Hs5[5] = {80, 40, 20, 10, 5};
  int loffs[5] = {0, 57600, 72000, 75600, 76500};
  const unsigned short* feats[5] = {p3, p4, p5, xp6, xp7};

  auto towerP = [&](int layer, const unsigned short* const* xc, const unsigned short* const* xr,
                    unsigned short* yc_base, unsigned short* yr_base) {
    LvlParams P{};
    fill(P, 5, Hs5);
    for (int L = 0; L < 5; ++L) {
      P.ncb[L] = 8;
      P.x0[L] = xc[L];
      P.x1[L] = xr[L];
      P.w0[L] = ws + W_CW0 + layer * 589824;
      P.w1[L] = ws + W_RW0 + layer * 589824;
      P.b0[L] = cbf[layer];
      P.b1[L] = rbf[layer];
      P.y0[L] = yc_base + TL_OFF[L];
      P.y1[L] = yr_base + TL_OFF[L];
    }
    conv_mfma<9, 0><<<dim3(P.nbcum[5], 4, 2), 256, 0, stream>>>(P, 256, 256, 1, nullptr, zbuf);
  };

  const unsigned short* t0c_l[5], *t1c_l[5], *t0r_l[5], *t1r_l[5];
  for (int L = 0; L < 5; ++L) {
    t0c_l[L] = t0c + TL_OFF[L];
    t1c_l[L] = t1c + TL_OFF[L];
    t0r_l[L] = t0r + TL_OFF[L];
    t1r_l[L] = t1r + TL_OFF[L];
  }
  towerP(0, feats, feats, t0c, t0r);
  towerP(1, t0c_l, t0r_l, t1c, t1r);
  towerP(2, t1c_l, t1r_l, t0c, t0r);
  towerP(3, t0c_l, t0r_l, t1c, t1r);

  // ---- reg header first (reads t1r in d_out, writes LOC) ----
  {
    LvlParams P{};
    fill(P, 5, Hs5);
    for (int L = 0; L < 5; ++L) {
      P.ncb[L] = 8;
      P.x0[L] = t1r_l[L];
      P.w0[L] = ws + W_RHW;
      P.b0[L] = rhb;
      P.loff[L] = loffs[L];
    }
    conv_mfma<9, 2><<<dim3(P.nbcum[5], 1, 1), 256, 0, stream>>>(P, 64, 36, 0, out + LOC_BASE, zbuf);
  }
  // ---- cls header (reads t1c in ws, writes cls region) ----
  {
    LvlParams P{};
    fill(P, 5, Hs5);
    for (int L = 0; L < 5; ++L) {
      P.ncb[L] = 8;
      P.x0[L] = t1c_l[L];
      P.w0[L] = ws + W_CHW;
      P.b0[L] = chb;
      P.loff[L] = loffs[L];
    }
    conv_mfma<9, 1><<<dim3(P.nbcum[5], 12, 1), 256, 0, stream>>>(P, 768, 720, 0, out, zbuf);
  }

  anchors_kernel<<<dim3((NA_TOT + 255) / 256), 256, 0, stream>>>(out + ANC_BASE);
}

// Round 6
// 867.545 us; speedup vs baseline: 20.7597x; 1.0196x over previous
//
#include <hip/hip_runtime.h>
#include <math.h>

#define NA_TOT 76725
#define NCLS 80
#define LOC_BASE 12276000
#define ANC_BASE 12889800

typedef short s16x8 __attribute__((ext_vector_type(8)));
typedef short s16x4 __attribute__((ext_vector_type(4)));
typedef float fx4 __attribute__((ext_vector_type(4)));

__device__ __forceinline__ unsigned short f2bf(float f) {
  unsigned u = __float_as_uint(f);
  unsigned r = (u + 0x7FFFu + ((u >> 16) & 1u)) >> 16;
  return (unsigned short)r;
}
__device__ __forceinline__ float bf2f(unsigned short h) {
  return __uint_as_float(((unsigned)h) << 16);
}

__global__ void zk(unsigned short* z) { z[threadIdx.x] = 0; }

// weight convert fp32 [O][Cin][taps] -> bf16 [tap][cb][Opad][32], zero-padded rows
__global__ __launch_bounds__(256) void wconv(const float* __restrict__ src, unsigned short* __restrict__ dst,
                                             int O, int Opad, int Cin, int taps, int ncb) {
  int idx = blockIdx.x * 256 + threadIdx.x;
  int tot = taps * ncb * Opad * 32;
  if (idx >= tot) return;
  int c32 = idx & 31;
  int r = idx >> 5;
  int o = r % Opad;
  int q = r / Opad;
  int cb = q % ncb;
  int tp = q / ncb;
  int c = cb * 32 + c32;
  float v = (o < O) ? src[((size_t)o * Cin + c) * taps + tp] : 0.f;
  dst[idx] = f2bf(v);
}

// NCHW fp32 -> blocked [b][C/32][HW][32] bf16
__global__ __launch_bounds__(256) void nchw2blk(const float* __restrict__ x, unsigned short* __restrict__ y,
                                                int C, int HW) {
  __shared__ float tile[32][65];
  int pb = blockIdx.x * 64, cb = blockIdx.y, b = blockIdx.z;
  int C32 = C >> 5;
  int t = threadIdx.x;
#pragma unroll
  for (int k = 0; k < 8; ++k) {
    int idx = k * 256 + t;
    int c = idx >> 6, p = idx & 63;
    if (pb + p < HW) tile[c][p] = x[((size_t)b * C + cb * 32 + c) * HW + pb + p];
  }
  __syncthreads();
  int pix = t >> 2, co = (t & 3) * 8;
  if (pb + pix < HW) {
    s16x8 v;
#pragma unroll
    for (int j = 0; j < 8; ++j) v[j] = (short)f2bf(tile[co + j][pix]);
    *(s16x8*)(y + (((size_t)b * C32 + cb) * HW + pb + pix) * 32 + co) = v;
  }
}

// nearest 2x upsample + add, blocked layout
__global__ __launch_bounds__(256) void up2add(unsigned short* __restrict__ dst, const unsigned short* __restrict__ src,
                                              int C32, int H, int W) {
  int idx = blockIdx.x * 256 + threadIdx.x;
  int HW = H * W;
  int tot = 2 * C32 * HW * 4;
  if (idx >= tot) return;
  int cv = idx & 3;
  int t = idx >> 2;
  int p = t % HW; t /= HW;
  int cb = t % C32;
  int b = t / C32;
  int h = p / W, w = p - h * W;
  int Hs = H >> 1, Ws = W >> 1;
  size_t di = (((size_t)b * C32 + cb) * HW + p) * 32 + cv * 8;
  size_t si = (((size_t)b * C32 + cb) * (Hs * Ws) + (h >> 1) * Ws + (w >> 1)) * 32 + cv * 8;
  s16x8 d = *(s16x8*)(dst + di);
  s16x8 s = *(const s16x8*)(src + si);
  s16x8 r;
#pragma unroll
  for (int j = 0; j < 8; ++j)
    r[j] = (short)f2bf(bf2f((unsigned short)d[j]) + bf2f((unsigned short)s[j]));
  *(s16x8*)(dst + di) = r;
}

// ---------------- fused multi-level MFMA conv, mega-staged ----------------
// Block 256 thr = 4 waves: wm = Cout half (2x64), wn = row pair (2x2 rows).
// Block tile: 128 Cout x (4 rows x 16 cols). Whole 8-cb halo staged to LDS at
// once -> ONE vmcnt(0)+barrier, then a barrier-free fully-unrolled 8cb x TAPS
// MFMA run (compiler pipelines ds_read/lgkmcnt + hoists A loads freely).
struct LvlParams {
  int nlev;
  int nbcum[6];
  int H[5], W[5], CT[5], RT[5], ncb[5], loff[5];
  const unsigned short* x0[5];
  const unsigned short* x1[5];
  const unsigned short* w0[5];
  const unsigned short* w1[5];
  const float* b0[5];
  const float* b1[5];
  unsigned short* y0[5];
  unsigned short* y1[5];
};

template <int TAPS, int MODE>
__global__ __launch_bounds__(256, 2) void conv_mfma(
    LvlParams P, int Opad, int O, int relu, float* __restrict__ fout,
    const unsigned short* __restrict__ zbuf) {
  constexpr int HO = (TAPS == 9) ? 1 : 0;
  constexpr int RH = 4 + 2 * HO;
  constexpr int CW = 16 + 2 * HO;
  constexpr int NPIX = RH * CW;                 // 108 or 64
  constexpr int PADPX = (TAPS == 9) ? 112 : 64; // mult of 8 keeps swizzle key
  constexpr int NS = PADPX / 8;                 // issues per wave (14 or 8)

  int bx = blockIdx.x;
  int L = 0;
  while (L + 1 < P.nlev && bx >= P.nbcum[L + 1]) ++L;
  int nb = bx - P.nbcum[L];
  int H = P.H[L], W = P.W[L], CT = P.CT[L], RT = P.RT[L];
  int ncbL = P.ncb[L];
  int G = ncbL >> 3;
  int HW = H * W;
  int ct = nb % CT;
  int tmp = nb / CT;
  int rt = tmp % RT;
  int b = tmp / RT;
  int set = blockIdx.z;
  const unsigned short* x = set ? P.x1[L] : P.x0[L];
  const unsigned short* wgt = set ? P.w1[L] : P.w0[L];
  const float* bias = set ? P.b1[L] : P.b0[L];
  unsigned short* y = set ? P.y1[L] : P.y0[L];

  int tid = threadIdx.x;
  int lane = tid & 63, wv = tid >> 6;
  int wm = wv & 1, wn = wv >> 1;
  int l15 = lane & 15, l4 = lane >> 4;

  __shared__ unsigned short halo[8 * PADPX * 32];

  int r0 = rt * 4 - HO, c0 = ct * 16 - HO;
  int obase = blockIdx.y * 128 + wm * 64;

  fx4 acc[4][2];
#pragma unroll
  for (int i = 0; i < 4; ++i)
#pragma unroll
    for (int f = 0; f < 2; ++f) acc[i][f] = fx4{0.f, 0.f, 0.f, 0.f};

  // stage all 8 cbs of group g into LDS
  auto stage = [&](int g) {
#pragma unroll
    for (int s = 0; s < NS; ++s) {
      int ib = wv * (NS * 16) + s * 16;
      int slotq = ib + (lane >> 2);
      int cbq = slotq / PADPX;
      int px = slotq - cbq * PADPX;
      int hr = px / CW, hc = px - hr * CW;
      int h = r0 + hr, wq = c0 + hc;
      bool ok = (px < NPIX) && (h >= 0) && (h < H) && (wq >= 0) && (wq < W);
      int cs = (lane & 3) ^ ((px >> 1) & 3);  // pre-swizzled source chunk
      int cb = g * 8 + cbq;
      const unsigned short* src =
          ok ? (x + (((size_t)b * ncbL + cb) * HW + (h * W + wq)) * 32 + cs * 8) : zbuf;
      unsigned short* dst = &halo[ib * 32];
      __builtin_amdgcn_global_load_lds((const __attribute__((address_space(1))) unsigned int*)src,
                                       (__attribute__((address_space(3))) unsigned int*)dst, 16, 0, 0);
    }
  };

  for (int g = 0; g < G; ++g) {
    stage(g);
    asm volatile("s_waitcnt vmcnt(0)" ::: "memory");
    __builtin_amdgcn_s_barrier();
#pragma unroll
    for (int cbq = 0; cbq < 8; ++cbq) {
#pragma unroll
      for (int t = 0; t < TAPS; ++t) {
        s16x8 a[4];
        int cb = g * 8 + cbq;
#pragma unroll
        for (int i = 0; i < 4; ++i)
          a[i] = *(const s16x8*)(wgt + (((size_t)t * ncbL + cb) * Opad + obase + i * 16 + l15) * 32 + l4 * 8);
        const int dy = (TAPS == 9) ? t / 3 : 0;
        const int dx = (TAPS == 9) ? t % 3 : 0;
#pragma unroll
        for (int f = 0; f < 2; ++f) {
          int hpix = (wn * 2 + f + dy) * CW + (l15 + dx);
          s16x8 bfr = *(const s16x8*)&halo[(cbq * PADPX + hpix) * 32 + ((l4 ^ ((hpix >> 1) & 3)) * 8)];
#pragma unroll
          for (int i = 0; i < 4; ++i)
            acc[i][f] = __builtin_amdgcn_mfma_f32_16x16x32_bf16(a[i], bfr, acc[i][f], 0, 0, 0);
        }
      }
    }
    if (g + 1 < G) __builtin_amdgcn_s_barrier();  // protect LDS before restage
  }

  int r_base = rt * 4 + wn * 2;
  int c_img = ct * 16 + l15;
  if (MODE == 0) {
    int OC32 = gridDim.y * 4;
#pragma unroll
    for (int i = 0; i < 4; ++i) {
      int o0 = obase + i * 16 + l4 * 4;
      fx4 b4 = *(const fx4*)(bias + o0);
#pragma unroll
      for (int f = 0; f < 2; ++f) {
        int r_img = r_base + f;
        if (r_img < H && c_img < W) {
          int p = r_img * W + c_img;
          size_t base = (((size_t)b * OC32 + (o0 >> 5)) * HW + p) * 32 + (o0 & 31);
          s16x4 pk;
#pragma unroll
          for (int j = 0; j < 4; ++j) {
            float v = acc[i][f][j] + b4[j];
            if (relu) v = fmaxf(v, 0.f);
            pk[j] = (short)f2bf(v);
          }
          *(s16x4*)(y + base) = pk;
        }
      }
    }
  } else if (MODE == 1) {
#pragma unroll
    for (int i = 0; i < 4; ++i) {
      int o0 = obase + i * 16 + l4 * 4;
#pragma unroll
      for (int f = 0; f < 2; ++f) {
        int r_img = r_base + f;
        if (r_img < H && c_img < W && o0 < O) {
          int p = r_img * W + c_img;
          int a_ = o0 / NCLS, c0i = o0 - a_ * NCLS;
          size_t n = (size_t)b * NA_TOT + P.loff[L] + (size_t)p * 9 + a_;
          fx4 v;
#pragma unroll
          for (int j = 0; j < 4; ++j)
            v[j] = 1.f / (1.f + __expf(-(acc[i][f][j] + bias[o0 + j])));
          *(fx4*)(fout + n * NCLS + c0i) = v;
        }
      }
    }
  } else {
#pragma unroll
    for (int i = 0; i < 4; ++i) {
      int o0 = obase + i * 16 + l4 * 4;
#pragma unroll
      for (int f = 0; f < 2; ++f) {
        int r_img = r_base + f;
        if (r_img < H && c_img < W && o0 < O) {
          int p = r_img * W + c_img;
          int a_ = o0 >> 2;
          size_t n = (size_t)b * NA_TOT + P.loff[L] + (size_t)p * 9 + a_;
          fx4 v;
#pragma unroll
          for (int j = 0; j < 4; ++j) v[j] = acc[i][f][j] + bias[o0 + j];
          *(fx4*)(fout + n * 4) = v;
        }
      }
    }
  }
}

__global__ __launch_bounds__(256) void anchors_kernel(float* __restrict__ out) {
  int n = blockIdx.x * blockDim.x + threadIdx.x;
  if (n >= NA_TOT) return;
  int rem, fw;
  float stride;
  if (n < 57600)      { rem = n;         fw = 80; stride = 8.f; }
  else if (n < 72000) { rem = n - 57600; fw = 40; stride = 16.f; }
  else if (n < 75600) { rem = n - 72000; fw = 20; stride = 32.f; }
  else if (n < 76500) { rem = n - 75600; fw = 10; stride = 64.f; }
  else                { rem = n - 76500; fw = 5;  stride = 128.f; }
  int k = rem % 9;
  int cell = rem / 9;
  int xg = cell % fw;
  int yg = cell / fw;
  const float scales[3] = {1.f, 1.2599210498948732f, 1.5874010519681994f};
  const float isr[3] = {1.4142135623730951f, 1.f, 0.70710678118654755f};
  const float sr[3]  = {0.70710678118654755f, 1.f, 1.4142135623730951f};
  int si = k % 3, ri = k / 3;
  float base = 4.f * stride;
  float wv = base * scales[si] * isr[ri];
  float hv = base * scales[si] * sr[ri];
  float cx = ((float)xg + 0.5f) * stride;
  float cy = ((float)yg + 0.5f) * stride;
  out[(size_t)n * 4 + 0] = cx - 0.5f * wv;
  out[(size_t)n * 4 + 1] = cy - 0.5f * hv;
  out[(size_t)n * 4 + 2] = cx + 0.5f * wv;
  out[(size_t)n * 4 + 3] = cy + 0.5f * hv;
}

// ---------------- ws layout (shorts) ----------------
#define W_FL1 0
#define W_FL2 524288
#define W_FL3 786432
#define W_FTD 917504
#define W_CW0 1507328
#define W_RW0 3866624
#define W_CHW 6225920
#define W_RHW 7995392
#define ZBUF_OFF 8290304
#define RA_OFF 8290368
#define P3_OFF 12655168
#define P4_OFF 15931968
#define P5_OFF 16751168
#define T0C_OFF 16955968
// end 21320768 shorts = 42.6 MB

static const int TL_OFF[5] = {0, 3276800, 4096000, 4300800, 4352000};

extern "C" void kernel_launch(void* const* d_in, const int* in_sizes, int n_in,
                              void* d_out, int out_size, void* d_ws, size_t ws_size,
                              hipStream_t stream) {
  const float* c3 = (const float*)d_in[0];
  const float* c4 = (const float*)d_in[1];
  const float* c5 = (const float*)d_in[2];
  const float* p6 = (const float*)d_in[3];
  const float* p7 = (const float*)d_in[4];
  const float* flw[3] = {(const float*)d_in[5], (const float*)d_in[7], (const float*)d_in[9]};
  const float* flb[3] = {(const float*)d_in[6], (const float*)d_in[8], (const float*)d_in[10]};
  const float* ftd_w = (const float*)d_in[11];
  const float* ftd_b = (const float*)d_in[12];
  const float* cwf[4] = {(const float*)d_in[13], (const float*)d_in[15], (const float*)d_in[17], (const float*)d_in[19]};
  const float* cbf[4] = {(const float*)d_in[14], (const float*)d_in[16], (const float*)d_in[18], (const float*)d_in[20]};
  const float* chw = (const float*)d_in[21];
  const float* chb = (const float*)d_in[22];
  const float* rwf[4] = {(const float*)d_in[23], (const float*)d_in[25], (const float*)d_in[27], (const float*)d_in[29]};
  const float* rbf[4] = {(const float*)d_in[24], (const float*)d_in[26], (const float*)d_in[28], (const float*)d_in[30]};
  const float* rhw = (const float*)d_in[31];
  const float* rhb = (const float*)d_in[32];

  unsigned short* ws = (unsigned short*)d_ws;
  unsigned short* zbuf = ws + ZBUF_OFF;
  float* out = (float*)d_out;

  unsigned short* ob = (unsigned short*)d_out;
  unsigned short* x3 = ob;
  unsigned short* x4 = ob + 6553600;
  unsigned short* x5 = ob + 9830400;
  unsigned short* t0r = ob;
  unsigned short* t1r = ob + 4364800;
  unsigned short* xp6 = ws + RA_OFF;
  unsigned short* xp7 = ws + RA_OFF + 51200;
  unsigned short* p4l = ws + RA_OFF + 64000;
  unsigned short* p5l = ws + RA_OFF + 883200;
  unsigned short* p3l = ws + RA_OFF + 1088000;
  unsigned short* t1c = ws + RA_OFF;
  unsigned short* t0c = ws + T0C_OFF;
  unsigned short* p3 = ws + P3_OFF;
  unsigned short* p4 = ws + P4_OFF;
  unsigned short* p5 = ws + P5_OFF;

  zk<<<1, 64, 0, stream>>>(zbuf);

  auto wc = [&](const float* s, unsigned short* d, int O, int Opad, int Cin, int taps) {
    int ncb = Cin / 32;
    int tot = taps * ncb * Opad * 32;
    wconv<<<(tot + 255) / 256, 256, 0, stream>>>(s, d, O, Opad, Cin, taps, ncb);
  };
  wc(flw[0], ws + W_FL1, 256, 256, 2048, 1);
  wc(flw[1], ws + W_FL2, 256, 256, 1024, 1);
  wc(flw[2], ws + W_FL3, 256, 256, 512, 1);
  wc(ftd_w, ws + W_FTD, 256, 256, 256, 9);
  for (int k = 0; k < 4; ++k) wc(cwf[k], ws + W_CW0 + k * 589824, 256, 256, 256, 9);
  for (int k = 0; k < 4; ++k) wc(rwf[k], ws + W_RW0 + k * 589824, 256, 256, 256, 9);
  wc(chw, ws + W_CHW, 720, 768, 256, 9);
  wc(rhw, ws + W_RHW, 36, 128, 256, 9);

  nchw2blk<<<dim3(100, 16, 2), 256, 0, stream>>>(c3, x3, 512, 6400);
  nchw2blk<<<dim3(25, 32, 2), 256, 0, stream>>>(c4, x4, 1024, 1600);
  nchw2blk<<<dim3(7, 64, 2), 256, 0, stream>>>(c5, x5, 2048, 400);
  nchw2blk<<<dim3(2, 8, 2), 256, 0, stream>>>(p6, xp6, 256, 100);
  nchw2blk<<<dim3(1, 8, 2), 256, 0, stream>>>(p7, xp7, 256, 25);

  auto fill = [](LvlParams& P, int nlev, const int* Hs) {
    P.nlev = nlev;
    int cum = 0;
    for (int L = 0; L < nlev; ++L) {
      P.nbcum[L] = cum;
      P.H[L] = Hs[L]; P.W[L] = Hs[L];
      P.CT[L] = (Hs[L] + 15) / 16;
      P.RT[L] = (Hs[L] + 3) / 4;
      cum += 2 * P.CT[L] * P.RT[L];
    }
    P.nbcum[nlev] = cum;
  };

  // ---- FPN laterals: 3 levels fused, 1x1 ----
  {
    int Hs[3] = {20, 40, 80};
    LvlParams P{};
    fill(P, 3, Hs);
    P.ncb[0] = 64; P.ncb[1] = 32; P.ncb[2] = 16;
    P.x0[0] = x5; P.x0[1] = x4; P.x0[2] = x3;
    P.w0[0] = ws + W_FL1; P.w0[1] = ws + W_FL2; P.w0[2] = ws + W_FL3;
    P.b0[0] = flb[0]; P.b0[1] = flb[1]; P.b0[2] = flb[2];
    P.y0[0] = p5l; P.y0[1] = p4l; P.y0[2] = p3l;
    conv_mfma<1, 0><<<dim3(P.nbcum[3], 2, 1), 256, 0, stream>>>(P, 256, 256, 0, nullptr, zbuf);
  }
  up2add<<<dim3((2 * 8 * 1600 * 4 + 255) / 256), 256, 0, stream>>>(p4l, p5l, 8, 40, 40);
  up2add<<<dim3((2 * 8 * 6400 * 4 + 255) / 256), 256, 0, stream>>>(p3l, p4l, 8, 80, 80);

  // ---- shared top-down 3x3 ----
  {
    int Hs[3] = {80, 40, 20};
    LvlParams P{};
    fill(P, 3, Hs);
    for (int L = 0; L < 3; ++L) {
      P.ncb[L] = 8;
      P.w0[L] = ws + W_FTD;
      P.b0[L] = ftd_b;
    }
    P.x0[0] = p3l; P.x0[1] = p4l; P.x0[2] = p5l;
    P.y0[0] = p3; P.y0[1] = p4; P.y0[2] = p5;
    conv_mfma<9, 0><<<dim3(P.nbcum[3], 2, 1), 256, 0, stream>>>(P, 256, 256, 0, nullptr, zbuf);
  }

  // ---- towers: 5 levels, cls(z=0)+reg(z=1) fused ----
  int Hs5[5] = {80, 40, 20, 10, 5};
  int loffs[5] = {0, 57600, 72000, 75600, 76500};
  const unsigned short* feats[5] = {p3, p4, p5, xp6, xp7};

  auto towerP = [&](int layer, const unsigned short* const* xc, const unsigned short* const* xr,
                    unsigned short* yc_base, unsigned short* yr_base) {
    LvlParams P{};
    fill(P, 5, Hs5);
    for (int L = 0; L < 5; ++L) {
      P.ncb[L] = 8;
      P.x0[L] = xc[L];
      P.x1[L] = xr[L];
      P.w0[L] = ws + W_CW0 + layer * 589824;
      P.w1[L] = ws + W_RW0 + layer * 589824;
      P.b0[L] = cbf[layer];
      P.b1[L] = rbf[layer];
      P.y0[L] = yc_base + TL_OFF[L];
      P.y1[L] = yr_base + TL_OFF[L];
    }
    conv_mfma<9, 0><<<dim3(P.nbcum[5], 2, 2), 256, 0, stream>>>(P, 256, 256, 1, nullptr, zbuf);
  };

  const unsigned short* t0c_l[5], *t1c_l[5], *t0r_l[5], *t1r_l[5];
  for (int L = 0; L < 5; ++L) {
    t0c_l[L] = t0c + TL_OFF[L];
    t1c_l[L] = t1c + TL_OFF[L];
    t0r_l[L] = t0r + TL_OFF[L];
    t1r_l[L] = t1r + TL_OFF[L];
  }
  towerP(0, feats, feats, t0c, t0r);
  towerP(1, t0c_l, t0r_l, t1c, t1r);
  towerP(2, t1c_l, t1r_l, t0c, t0r);
  towerP(3, t0c_l, t0r_l, t1c, t1r);

  // ---- reg header first (reads t1r in d_out, writes LOC) ----
  {
    LvlParams P{};
    fill(P, 5, Hs5);
    for (int L = 0; L < 5; ++L) {
      P.ncb[L] = 8;
      P.x0[L] = t1r_l[L];
      P.w0[L] = ws + W_RHW;
      P.b0[L] = rhb;
      P.loff[L] = loffs[L];
    }
    conv_mfma<9, 2><<<dim3(P.nbcum[5], 1, 1), 256, 0, stream>>>(P, 128, 36, 0, out + LOC_BASE, zbuf);
  }
  // ---- cls header (reads t1c in ws, writes cls region) ----
  {
    LvlParams P{};
    fill(P, 5, Hs5);
    for (int L = 0; L < 5; ++L) {
      P.ncb[L] = 8;
      P.x0[L] = t1c_l[L];
      P.w0[L] = ws + W_CHW;
      P.b0[L] = chb;
      P.loff[L] = loffs[L];
    }
    conv_mfma<9, 1><<<dim3(P.nbcum[5], 6, 1), 256, 0, stream>>>(P, 768, 720, 0, out, zbuf);
  }

  anchors_kernel<<<dim3((NA_TOT + 255) / 256), 256, 0, stream>>>(out + ANC_BASE);
}

// Round 7
// 638.237 us; speedup vs baseline: 28.2184x; 1.3593x over previous
//
#include <hip/hip_runtime.h>
#include <math.h>

#define NA_TOT 76725
#define NCLS 80
#define LOC_BASE 12276000
#define ANC_BASE 12889800

typedef short s16x8 __attribute__((ext_vector_type(8)));
typedef short s16x4 __attribute__((ext_vector_type(4)));
typedef float fx4 __attribute__((ext_vector_type(4)));

__device__ __forceinline__ unsigned short f2bf(float f) {
  unsigned u = __float_as_uint(f);
  unsigned r = (u + 0x7FFFu + ((u >> 16) & 1u)) >> 16;
  return (unsigned short)r;
}
__device__ __forceinline__ float bf2f(unsigned short h) {
  return __uint_as_float(((unsigned)h) << 16);
}

__global__ void zk(unsigned short* z) { z[threadIdx.x] = 0; }

// weight convert fp32 [O][Cin][taps] -> bf16 [tap][cb][Opad][32], zero-padded rows
__global__ __launch_bounds__(256) void wconv(const float* __restrict__ src, unsigned short* __restrict__ dst,
                                             int O, int Opad, int Cin, int taps, int ncb) {
  int idx = blockIdx.x * 256 + threadIdx.x;
  int tot = taps * ncb * Opad * 32;
  if (idx >= tot) return;
  int c32 = idx & 31;
  int r = idx >> 5;
  int o = r % Opad;
  int q = r / Opad;
  int cb = q % ncb;
  int tp = q / ncb;
  int c = cb * 32 + c32;
  float v = (o < O) ? src[((size_t)o * Cin + c) * taps + tp] : 0.f;
  dst[idx] = f2bf(v);
}

// NCHW fp32 -> blocked [b][C/32][HW][32] bf16
__global__ __launch_bounds__(256) void nchw2blk(const float* __restrict__ x, unsigned short* __restrict__ y,
                                                int C, int HW) {
  __shared__ float tile[32][65];
  int pb = blockIdx.x * 64, cb = blockIdx.y, b = blockIdx.z;
  int C32 = C >> 5;
  int t = threadIdx.x;
#pragma unroll
  for (int k = 0; k < 8; ++k) {
    int idx = k * 256 + t;
    int c = idx >> 6, p = idx & 63;
    if (pb + p < HW) tile[c][p] = x[((size_t)b * C + cb * 32 + c) * HW + pb + p];
  }
  __syncthreads();
  int pix = t >> 2, co = (t & 3) * 8;
  if (pb + pix < HW) {
    s16x8 v;
#pragma unroll
    for (int j = 0; j < 8; ++j) v[j] = (short)f2bf(tile[co + j][pix]);
    *(s16x8*)(y + (((size_t)b * C32 + cb) * HW + pb + pix) * 32 + co) = v;
  }
}

// nearest 2x upsample + add, blocked layout
__global__ __launch_bounds__(256) void up2add(unsigned short* __restrict__ dst, const unsigned short* __restrict__ src,
                                              int C32, int H, int W) {
  int idx = blockIdx.x * 256 + threadIdx.x;
  int HW = H * W;
  int tot = 2 * C32 * HW * 4;
  if (idx >= tot) return;
  int cv = idx & 3;
  int t = idx >> 2;
  int p = t % HW; t /= HW;
  int cb = t % C32;
  int b = t / C32;
  int h = p / W, w = p - h * W;
  int Hs = H >> 1, Ws = W >> 1;
  size_t di = (((size_t)b * C32 + cb) * HW + p) * 32 + cv * 8;
  size_t si = (((size_t)b * C32 + cb) * (Hs * Ws) + (h >> 1) * Ws + (w >> 1)) * 32 + cv * 8;
  s16x8 d = *(s16x8*)(dst + di);
  s16x8 s = *(const s16x8*)(src + si);
  s16x8 r;
#pragma unroll
  for (int j = 0; j < 8; ++j)
    r[j] = (short)f2bf(bf2f((unsigned short)d[j]) + bf2f((unsigned short)s[j]));
  *(s16x8*)(dst + di) = r;
}

// ---------------- fused multi-level MFMA conv ----------------
// Block 256 thr = 4 waves = 4 row-quads (wn). Block tile: 64 Cout x (16 rows x 16 cols).
// Wave tile: 64 Cout x 64 px -> acc[4][4]. One cb (32ch) halo per phase, dbuf LDS,
// T3-minimal 2-phase: stage(next); compute 9 taps x 16 MFMA; vmcnt(0); barrier.
struct LvlParams {
  int nlev;
  int nbcum[6];
  int H[5], W[5], CT[5], RT[5], ncb[5], loff[5];
  const unsigned short* x0[5];
  const unsigned short* x1[5];
  const unsigned short* w0[5];
  const unsigned short* w1[5];
  const float* b0[5];
  const float* b1[5];
  unsigned short* y0[5];
  unsigned short* y1[5];
};

template <int TAPS, int MODE>
__global__ __launch_bounds__(256, 3) void conv_mfma(
    LvlParams P, int Opad, int O, int relu, float* __restrict__ fout,
    const unsigned short* __restrict__ zbuf) {
  constexpr int HO = (TAPS == 9) ? 1 : 0;
  constexpr int CW = 16 + 2 * HO;         // 18 or 16
  constexpr int NPIX = CW * CW;           // 324 or 256
  constexpr int NS = (TAPS == 9) ? 6 : 4; // staging issues per wave
  constexpr int SLOTS = NS * 64;          // 384 or 256

  int bx = blockIdx.x;
  int L = 0;
  while (L + 1 < P.nlev && bx >= P.nbcum[L + 1]) ++L;
  int nb = bx - P.nbcum[L];
  int H = P.H[L], W = P.W[L], CT = P.CT[L], RT = P.RT[L];
  int ncbL = P.ncb[L];
  int HW = H * W;
  int ct = nb % CT;
  int tmp = nb / CT;
  int rt = tmp % RT;
  int b = tmp / RT;
  int set = blockIdx.z;
  const unsigned short* x = set ? P.x1[L] : P.x0[L];
  const unsigned short* wgt = set ? P.w1[L] : P.w0[L];
  const float* bias = set ? P.b1[L] : P.b0[L];
  unsigned short* y = set ? P.y1[L] : P.y0[L];

  int tid = threadIdx.x;
  int lane = tid & 63, wv = tid >> 6;
  int wn = wv;              // row-quad
  int l15 = lane & 15, l4 = lane >> 4;

  __shared__ unsigned short halo[2][SLOTS * 32];

  int r0 = rt * 16 - HO, c0 = ct * 16 - HO;
  int obase = blockIdx.y * 64;

  fx4 acc[4][4];
#pragma unroll
  for (int i = 0; i < 4; ++i)
#pragma unroll
    for (int f = 0; f < 4; ++f) acc[i][f] = fx4{0.f, 0.f, 0.f, 0.f};

  auto stage = [&](int buf, int cb) {
#pragma unroll
    for (int s = 0; s < NS; ++s) {
      int ib = wv * (NS * 16) + s * 16;
      int px = ib + (lane >> 2);
      int hr = px / CW, hc = px - hr * CW;
      int h = r0 + hr, wq = c0 + hc;
      bool ok = (px < NPIX) && (h >= 0) && (h < H) && (wq >= 0) && (wq < W);
      int cs = (lane & 3) ^ ((px >> 1) & 3);  // pre-swizzled source chunk
      const unsigned short* src =
          ok ? (x + (((size_t)b * ncbL + cb) * HW + (h * W + wq)) * 32 + cs * 8) : zbuf;
      unsigned short* dst = &halo[buf][ib * 32];
      __builtin_amdgcn_global_load_lds((const __attribute__((address_space(1))) unsigned int*)src,
                                       (__attribute__((address_space(3))) unsigned int*)dst, 16, 0, 0);
    }
  };

  stage(0, 0);
  asm volatile("s_waitcnt vmcnt(0)" ::: "memory");
  __builtin_amdgcn_s_barrier();

  for (int cb = 0; cb < ncbL; ++cb) {
    int cur = cb & 1;
    if (cb + 1 < ncbL) stage(cur ^ 1, cb + 1);
#pragma unroll
    for (int t = 0; t < TAPS; ++t) {
      const int dy = (TAPS == 9) ? t / 3 : 0;
      const int dx = (TAPS == 9) ? t % 3 : 0;
      s16x8 a[4];
#pragma unroll
      for (int i = 0; i < 4; ++i)
        a[i] = *(const s16x8*)(wgt + (((size_t)t * ncbL + cb) * Opad + obase + i * 16 + l15) * 32 + l4 * 8);
#pragma unroll
      for (int f = 0; f < 4; ++f) {
        int hpix = (wn * 4 + f + dy) * CW + (l15 + dx);
        s16x8 bfr = *(const s16x8*)&halo[cur][hpix * 32 + ((l4 ^ ((hpix >> 1) & 3)) * 8)];
#pragma unroll
        for (int i = 0; i < 4; ++i)
          acc[i][f] = __builtin_amdgcn_mfma_f32_16x16x32_bf16(a[i], bfr, acc[i][f], 0, 0, 0);
      }
    }
    asm volatile("s_waitcnt vmcnt(0)" ::: "memory");
    __builtin_amdgcn_s_barrier();
  }

  int r_base = rt * 16 + wn * 4;
  int c_img = ct * 16 + l15;
  if (MODE == 0) {
    int OC32 = gridDim.y * 2;
#pragma unroll
    for (int i = 0; i < 4; ++i) {
      int o0 = obase + i * 16 + l4 * 4;
      fx4 b4 = *(const fx4*)(bias + o0);
#pragma unroll
      for (int f = 0; f < 4; ++f) {
        int r_img = r_base + f;
        if (r_img < H && c_img < W) {
          int p = r_img * W + c_img;
          size_t base = (((size_t)b * OC32 + (o0 >> 5)) * HW + p) * 32 + (o0 & 31);
          s16x4 pk;
#pragma unroll
          for (int j = 0; j < 4; ++j) {
            float v = acc[i][f][j] + b4[j];
            if (relu) v = fmaxf(v, 0.f);
            pk[j] = (short)f2bf(v);
          }
          *(s16x4*)(y + base) = pk;
        }
      }
    }
  } else if (MODE == 1) {
#pragma unroll
    for (int i = 0; i < 4; ++i) {
      int o0 = obase + i * 16 + l4 * 4;
#pragma unroll
      for (int f = 0; f < 4; ++f) {
        int r_img = r_base + f;
        if (r_img < H && c_img < W && o0 < O) {
          int p = r_img * W + c_img;
          int a_ = o0 / NCLS, c0i = o0 - a_ * NCLS;
          size_t n = (size_t)b * NA_TOT + P.loff[L] + (size_t)p * 9 + a_;
          fx4 v;
#pragma unroll
          for (int j = 0; j < 4; ++j)
            v[j] = 1.f / (1.f + __expf(-(acc[i][f][j] + bias[o0 + j])));
          *(fx4*)(fout + n * NCLS + c0i) = v;
        }
      }
    }
  } else {
#pragma unroll
    for (int i = 0; i < 4; ++i) {
      int o0 = obase + i * 16 + l4 * 4;
#pragma unroll
      for (int f = 0; f < 4; ++f) {
        int r_img = r_base + f;
        if (r_img < H && c_img < W && o0 < O) {
          int p = r_img * W + c_img;
          int a_ = o0 >> 2;
          size_t n = (size_t)b * NA_TOT + P.loff[L] + (size_t)p * 9 + a_;
          fx4 v;
#pragma unroll
          for (int j = 0; j < 4; ++j) v[j] = acc[i][f][j] + bias[o0 + j];
          *(fx4*)(fout + n * 4) = v;
        }
      }
    }
  }
}

__global__ __launch_bounds__(256) void anchors_kernel(float* __restrict__ out) {
  int n = blockIdx.x * blockDim.x + threadIdx.x;
  if (n >= NA_TOT) return;
  int rem, fw;
  float stride;
  if (n < 57600)      { rem = n;         fw = 80; stride = 8.f; }
  else if (n < 72000) { rem = n - 57600; fw = 40; stride = 16.f; }
  else if (n < 75600) { rem = n - 72000; fw = 20; stride = 32.f; }
  else if (n < 76500) { rem = n - 75600; fw = 10; stride = 64.f; }
  else                { rem = n - 76500; fw = 5;  stride = 128.f; }
  int k = rem % 9;
  int cell = rem / 9;
  int xg = cell % fw;
  int yg = cell / fw;
  const float scales[3] = {1.f, 1.2599210498948732f, 1.5874010519681994f};
  const float isr[3] = {1.4142135623730951f, 1.f, 0.70710678118654755f};
  const float sr[3]  = {0.70710678118654755f, 1.f, 1.4142135623730951f};
  int si = k % 3, ri = k / 3;
  float base = 4.f * stride;
  float wv = base * scales[si] * isr[ri];
  float hv = base * scales[si] * sr[ri];
  float cx = ((float)xg + 0.5f) * stride;
  float cy = ((float)yg + 0.5f) * stride;
  out[(size_t)n * 4 + 0] = cx - 0.5f * wv;
  out[(size_t)n * 4 + 1] = cy - 0.5f * hv;
  out[(size_t)n * 4 + 2] = cx + 0.5f * wv;
  out[(size_t)n * 4 + 3] = cy + 0.5f * hv;
}

// ---------------- ws layout (shorts) ----------------
#define W_FL1 0
#define W_FL2 524288
#define W_FL3 786432
#define W_FTD 917504
#define W_CW0 1507328
#define W_RW0 3866624
#define W_CHW 6225920
#define W_RHW 7995392
#define ZBUF_OFF 8290304
#define RA_OFF 8290368
#define P3_OFF 12655168
#define P4_OFF 15931968
#define P5_OFF 16751168
#define T0C_OFF 16955968
// end 21320768 shorts = 42.6 MB

static const int TL_OFF[5] = {0, 3276800, 4096000, 4300800, 4352000};

extern "C" void kernel_launch(void* const* d_in, const int* in_sizes, int n_in,
                              void* d_out, int out_size, void* d_ws, size_t ws_size,
                              hipStream_t stream) {
  const float* c3 = (const float*)d_in[0];
  const float* c4 = (const float*)d_in[1];
  const float* c5 = (const float*)d_in[2];
  const float* p6 = (const float*)d_in[3];
  const float* p7 = (const float*)d_in[4];
  const float* flw[3] = {(const float*)d_in[5], (const float*)d_in[7], (const float*)d_in[9]};
  const float* flb[3] = {(const float*)d_in[6], (const float*)d_in[8], (const float*)d_in[10]};
  const float* ftd_w = (const float*)d_in[11];
  const float* ftd_b = (const float*)d_in[12];
  const float* cwf[4] = {(const float*)d_in[13], (const float*)d_in[15], (const float*)d_in[17], (const float*)d_in[19]};
  const float* cbf[4] = {(const float*)d_in[14], (const float*)d_in[16], (const float*)d_in[18], (const float*)d_in[20]};
  const float* chw = (const float*)d_in[21];
  const float* chb = (const float*)d_in[22];
  const float* rwf[4] = {(const float*)d_in[23], (const float*)d_in[25], (const float*)d_in[27], (const float*)d_in[29]};
  const float* rbf[4] = {(const float*)d_in[24], (const float*)d_in[26], (const float*)d_in[28], (const float*)d_in[30]};
  const float* rhw = (const float*)d_in[31];
  const float* rhb = (const float*)d_in[32];

  unsigned short* ws = (unsigned short*)d_ws;
  unsigned short* zbuf = ws + ZBUF_OFF;
  float* out = (float*)d_out;

  unsigned short* ob = (unsigned short*)d_out;
  unsigned short* x3 = ob;
  unsigned short* x4 = ob + 6553600;
  unsigned short* x5 = ob + 9830400;
  unsigned short* t0r = ob;
  unsigned short* t1r = ob + 4364800;
  unsigned short* xp6 = ws + RA_OFF;
  unsigned short* xp7 = ws + RA_OFF + 51200;
  unsigned short* p4l = ws + RA_OFF + 64000;
  unsigned short* p5l = ws + RA_OFF + 883200;
  unsigned short* p3l = ws + RA_OFF + 1088000;
  unsigned short* t1c = ws + RA_OFF;
  unsigned short* t0c = ws + T0C_OFF;
  unsigned short* p3 = ws + P3_OFF;
  unsigned short* p4 = ws + P4_OFF;
  unsigned short* p5 = ws + P5_OFF;

  zk<<<1, 64, 0, stream>>>(zbuf);

  auto wc = [&](const float* s, unsigned short* d, int O, int Opad, int Cin, int taps) {
    int ncb = Cin / 32;
    int tot = taps * ncb * Opad * 32;
    wconv<<<(tot + 255) / 256, 256, 0, stream>>>(s, d, O, Opad, Cin, taps, ncb);
  };
  wc(flw[0], ws + W_FL1, 256, 256, 2048, 1);
  wc(flw[1], ws + W_FL2, 256, 256, 1024, 1);
  wc(flw[2], ws + W_FL3, 256, 256, 512, 1);
  wc(ftd_w, ws + W_FTD, 256, 256, 256, 9);
  for (int k = 0; k < 4; ++k) wc(cwf[k], ws + W_CW0 + k * 589824, 256, 256, 256, 9);
  for (int k = 0; k < 4; ++k) wc(rwf[k], ws + W_RW0 + k * 589824, 256, 256, 256, 9);
  wc(chw, ws + W_CHW, 720, 768, 256, 9);
  wc(rhw, ws + W_RHW, 36, 64, 256, 9);

  nchw2blk<<<dim3(100, 16, 2), 256, 0, stream>>>(c3, x3, 512, 6400);
  nchw2blk<<<dim3(25, 32, 2), 256, 0, stream>>>(c4, x4, 1024, 1600);
  nchw2blk<<<dim3(7, 64, 2), 256, 0, stream>>>(c5, x5, 2048, 400);
  nchw2blk<<<dim3(2, 8, 2), 256, 0, stream>>>(p6, xp6, 256, 100);
  nchw2blk<<<dim3(1, 8, 2), 256, 0, stream>>>(p7, xp7, 256, 25);

  auto fill = [](LvlParams& P, int nlev, const int* Hs) {
    P.nlev = nlev;
    int cum = 0;
    for (int L = 0; L < nlev; ++L) {
      P.nbcum[L] = cum;
      P.H[L] = Hs[L]; P.W[L] = Hs[L];
      P.CT[L] = (Hs[L] + 15) / 16;
      P.RT[L] = (Hs[L] + 15) / 16;
      cum += 2 * P.CT[L] * P.RT[L];
    }
    P.nbcum[nlev] = cum;
  };

  // ---- FPN laterals: 3 levels fused, 1x1 ----
  {
    int Hs[3] = {20, 40, 80};
    LvlParams P{};
    fill(P, 3, Hs);
    P.ncb[0] = 64; P.ncb[1] = 32; P.ncb[2] = 16;
    P.x0[0] = x5; P.x0[1] = x4; P.x0[2] = x3;
    P.w0[0] = ws + W_FL1; P.w0[1] = ws + W_FL2; P.w0[2] = ws + W_FL3;
    P.b0[0] = flb[0]; P.b0[1] = flb[1]; P.b0[2] = flb[2];
    P.y0[0] = p5l; P.y0[1] = p4l; P.y0[2] = p3l;
    conv_mfma<1, 0><<<dim3(P.nbcum[3], 4, 1), 256, 0, stream>>>(P, 256, 256, 0, nullptr, zbuf);
  }
  up2add<<<dim3((2 * 8 * 1600 * 4 + 255) / 256), 256, 0, stream>>>(p4l, p5l, 8, 40, 40);
  up2add<<<dim3((2 * 8 * 6400 * 4 + 255) / 256), 256, 0, stream>>>(p3l, p4l, 8, 80, 80);

  // ---- shared top-down 3x3 ----
  {
    int Hs[3] = {80, 40, 20};
    LvlParams P{};
    fill(P, 3, Hs);
    for (int L = 0; L < 3; ++L) {
      P.ncb[L] = 8;
      P.w0[L] = ws + W_FTD;
      P.b0[L] = ftd_b;
    }
    P.x0[0] = p3l; P.x0[1] = p4l; P.x0[2] = p5l;
    P.y0[0] = p3; P.y0[1] = p4; P.y0[2] = p5;
    conv_mfma<9, 0><<<dim3(P.nbcum[3], 4, 1), 256, 0, stream>>>(P, 256, 256, 0, nullptr, zbuf);
  }

  // ---- towers: 5 levels, cls(z=0)+reg(z=1) fused ----
  int Hs5[5] = {80, 40, 20, 10, 5};
  int loffs[5] = {0, 57600, 72000, 75600, 76500};
  const unsigned short* feats[5] = {p3, p4, p5, xp6, xp7};

  auto towerP = [&](int layer, const unsigned short* const* xc, const unsigned short* const* xr,
                    unsigned short* yc_base, unsigned short* yr_base) {
    LvlParams P{};
    fill(P, 5, Hs5);
    for (int L = 0; L < 5; ++L) {
      P.ncb[L] = 8;
      P.x0[L] = xc[L];
      P.x1[L] = xr[L];
      P.w0[L] = ws + W_CW0 + layer * 589824;
      P.w1[L] = ws + W_RW0 + layer * 589824;
      P.b0[L] = cbf[layer];
      P.b1[L] = rbf[layer];
      P.y0[L] = yc_base + TL_OFF[L];
      P.y1[L] = yr_base + TL_OFF[L];
    }
    conv_mfma<9, 0><<<dim3(P.nbcum[5], 4, 2), 256, 0, stream>>>(P, 256, 256, 1, nullptr, zbuf);
  };

  const unsigned short* t0c_l[5], *t1c_l[5], *t0r_l[5], *t1r_l[5];
  for (int L = 0; L < 5; ++L) {
    t0c_l[L] = t0c + TL_OFF[L];
    t1c_l[L] = t1c + TL_OFF[L];
    t0r_l[L] = t0r + TL_OFF[L];
    t1r_l[L] = t1r + TL_OFF[L];
  }
  towerP(0, feats, feats, t0c, t0r);
  towerP(1, t0c_l, t0r_l, t1c, t1r);
  towerP(2, t1c_l, t1r_l, t0c, t0r);
  towerP(3, t0c_l, t0r_l, t1c, t1r);

  // ---- reg header first (reads t1r in d_out, writes LOC) ----
  {
    LvlParams P{};
    fill(P, 5, Hs5);
    for (int L = 0; L < 5; ++L) {
      P.ncb[L] = 8;
      P.x0[L] = t1r_l[L];
      P.w0[L] = ws + W_RHW;
      P.b0[L] = rhb;
      P.loff[L] = loffs[L];
    }
    conv_mfma<9, 2><<<dim3(P.nbcum[5], 1, 1), 256, 0, stream>>>(P, 64, 36, 0, out + LOC_BASE, zbuf);
  }
  // ---- cls header (reads t1c in ws, writes cls region) ----
  {
    LvlParams P{};
    fill(P, 5, Hs5);
    for (int L = 0; L < 5; ++L) {
      P.ncb[L] = 8;
      P.x0[L] = t1c_l[L];
      P.w0[L] = ws + W_CHW;
      P.b0[L] = chb;
      P.loff[L] = loffs[L];
    }
    conv_mfma<9, 1><<<dim3(P.nbcum[5], 12, 1), 256, 0, stream>>>(P, 768, 720, 0, out, zbuf);
  }

  anchors_kernel<<<dim3((NA_TOT + 255) / 256), 256, 0, stream>>>(out + ANC_BASE);
}